// Round 1
// baseline (8037.500 us; speedup 1.0000x reference)
//
#include <hip/hip_runtime.h>
#include <hip/hip_bf16.h>
#include <math.h>

#define B_   64
#define TOK_ 64
#define NT_  456
#define L_   457
#define D_   256
#define H_   8
#define HD_  32
#define FF_  1024
#define NL_  4
#define PH_  32

// ---------------------------------------------------------------------------
// Generic tiled SGEMM: C[M,N] = A[M,K] @ W[K,N] + bias, optional relu,
// optional embed row-remap (orow = row + row/456 + 1).
// Requires M%64==0, N%64==0, K%16==0.
// ---------------------------------------------------------------------------
__global__ __launch_bounds__(256) void sgemm_kernel(
    const float* __restrict__ A, const float* __restrict__ W,
    const float* __restrict__ bias, float* __restrict__ C,
    int M, int N, int K, int relu, int remap)
{
    __shared__ float As[16][64];
    __shared__ float Bs[16][64];
    int tid = threadIdx.x;
    int rowblk = blockIdx.y * 64;
    int colblk = blockIdx.x * 64;

    int a_row = tid & 63, a_q = tid >> 6;       // A loader: row, k-quad
    int b_kr  = tid >> 4, b_cg = tid & 15;      // B loader: k-row, col-group
    int rm = tid >> 4, cn = tid & 15;           // compute: 4 rows, 4 cols

    float acc[4][4] = {};
    const float* Aptr = A + (size_t)(rowblk + a_row) * K;

    for (int kt = 0; kt < K; kt += 16) {
        float4 av = *(const float4*)(Aptr + kt + a_q * 4);
        float4 bv = *(const float4*)(W + (size_t)(kt + b_kr) * N + colblk + b_cg * 4);
        As[a_q * 4 + 0][a_row] = av.x;
        As[a_q * 4 + 1][a_row] = av.y;
        As[a_q * 4 + 2][a_row] = av.z;
        As[a_q * 4 + 3][a_row] = av.w;
        *(float4*)&Bs[b_kr][b_cg * 4] = bv;
        __syncthreads();
#pragma unroll
        for (int kk = 0; kk < 16; ++kk) {
            float4 a4 = *(const float4*)&As[kk][rm * 4];
            float4 b4 = *(const float4*)&Bs[kk][cn * 4];
            float ar[4] = {a4.x, a4.y, a4.z, a4.w};
            float br[4] = {b4.x, b4.y, b4.z, b4.w};
#pragma unroll
            for (int i = 0; i < 4; ++i)
#pragma unroll
                for (int j = 0; j < 4; ++j)
                    acc[i][j] += ar[i] * br[j];
        }
        __syncthreads();
    }

    float4 bv = *(const float4*)(bias + colblk + cn * 4);
    float bb[4] = {bv.x, bv.y, bv.z, bv.w};
#pragma unroll
    for (int i = 0; i < 4; ++i) {
        int grow = rowblk + rm * 4 + i;
        size_t orow = remap ? (size_t)(grow + grow / NT_ + 1) : (size_t)grow;
        float4 r;
        float v0 = acc[i][0] + bb[0];
        float v1 = acc[i][1] + bb[1];
        float v2 = acc[i][2] + bb[2];
        float v3 = acc[i][3] + bb[3];
        if (relu) {
            v0 = fmaxf(v0, 0.f); v1 = fmaxf(v1, 0.f);
            v2 = fmaxf(v2, 0.f); v3 = fmaxf(v3, 0.f);
        }
        r.x = v0; r.y = v1; r.z = v2; r.w = v3;
        *(float4*)(C + orow * N + colblk + cn * 4) = r;
    }
}

// ---------------------------------------------------------------------------
// CLS row: X[b,0,:] = coords[b] @ w_cls + b_cls
// ---------------------------------------------------------------------------
__global__ __launch_bounds__(256) void cls_kernel(
    const float* __restrict__ coords, const float* __restrict__ w_cls,
    const float* __restrict__ b_cls, float* __restrict__ X)
{
    int b = blockIdx.x;
    int t = threadIdx.x;
    float c0 = coords[b * 3 + 0], c1 = coords[b * 3 + 1], c2 = coords[b * 3 + 2];
    X[(size_t)b * L_ * D_ + t] =
        c0 * w_cls[t] + c1 * w_cls[D_ + t] + c2 * w_cls[2 * D_ + t] + b_cls[t];
}

// ---------------------------------------------------------------------------
// Attention: per (b,h,qtile of 32 rows). Full score row in LDS, 2-pass.
// qkv layout per row: [q(256) | k(256) | v(256)], head h at offset h*32.
// ---------------------------------------------------------------------------
__global__ __launch_bounds__(256) void attn_kernel(
    const float* __restrict__ qkv, float* __restrict__ out)
{
    int qt = blockIdx.x, h = blockIdx.y, b = blockIdx.z;
    __shared__ float Qs[32][32];
    __shared__ float Ks[64][32];
    __shared__ float Vs[64][32];
    __shared__ float Sc[32][460];

    int tid = threadIdx.x;
    int q0 = qt * 32;
    int qn = min(32, L_ - q0);
    const float scale = 0.17677669529663687f;  // 1/sqrt(32)
    float slope = (h < 4) ? 1.0f : 0.5f;
    const float* base = qkv + (size_t)b * L_ * 768;

    // Load Q tile (zero-fill beyond qn)
    {
        int i = tid >> 3, d4 = (tid & 7) * 4;
        float4 v = make_float4(0.f, 0.f, 0.f, 0.f);
        if (i < qn) v = *(const float4*)(base + (size_t)(q0 + i) * 768 + h * 32 + d4);
        *(float4*)&Qs[i][d4] = v;
    }

    int ri = tid >> 4;   // 0..15 -> rows 2ri, 2ri+1
    int cj = tid & 15;   // col group

    // ---- pass 1: scores ----
    for (int kt = 0; kt < 8; ++kt) {
        int k0 = kt * 64;
        int kn = min(64, L_ - k0);
        for (int idx = tid; idx < 512; idx += 256) {
            int j = idx >> 3, d4 = (idx & 7) * 4;
            float4 v = make_float4(0.f, 0.f, 0.f, 0.f);
            if (j < kn) v = *(const float4*)(base + (size_t)(k0 + j) * 768 + 256 + h * 32 + d4);
            *(float4*)&Ks[j][d4] = v;
        }
        __syncthreads();

        float s[2][4] = {};
#pragma unroll
        for (int d4 = 0; d4 < 32; d4 += 4) {
            float4 qa = *(const float4*)&Qs[2 * ri][d4];
            float4 qb = *(const float4*)&Qs[2 * ri + 1][d4];
#pragma unroll
            for (int u = 0; u < 4; ++u) {
                float4 kv = *(const float4*)&Ks[4 * cj + u][d4];
                s[0][u] += qa.x * kv.x + qa.y * kv.y + qa.z * kv.z + qa.w * kv.w;
                s[1][u] += qb.x * kv.x + qb.y * kv.y + qb.z * kv.z + qb.w * kv.w;
            }
        }
#pragma unroll
        for (int r = 0; r < 2; ++r) {
            int i = 2 * ri + r;
            int qpos = q0 + i;
#pragma unroll
            for (int u = 0; u < 4; ++u) {
                int jg = k0 + 4 * cj + u;
                if (jg < L_) {
                    float val = s[r][u] * scale - slope * fabsf((float)(qpos - jg));
                    Sc[i][jg] = val;
                }
            }
        }
        __syncthreads();
    }

    // zero the 457..459 pad (read by float4 in PV)
    if (tid < 32 * 3) {
        int i = tid / 3, p = tid % 3;
        Sc[i][L_ + p] = 0.f;
    }

    // ---- softmax per row (8 lanes per row) ----
    {
        int i = tid >> 3, g = tid & 7;
        if (i < qn) {
            float m = -1e30f;
            for (int j = g; j < L_; j += 8) m = fmaxf(m, Sc[i][j]);
#pragma unroll
            for (int o = 1; o < 8; o <<= 1) m = fmaxf(m, __shfl_xor(m, o));
            float sum = 0.f;
            for (int j = g; j < L_; j += 8) {
                float e = expf(Sc[i][j] - m);
                Sc[i][j] = e;
                sum += e;
            }
#pragma unroll
            for (int o = 1; o < 8; o <<= 1) sum += __shfl_xor(sum, o);
            float inv = 1.0f / sum;
            for (int j = g; j < L_; j += 8) Sc[i][j] *= inv;
        }
    }
    __syncthreads();

    // ---- pass 2: P @ V ----
    float o00 = 0.f, o01 = 0.f, o10 = 0.f, o11 = 0.f;
    int c2 = 2 * cj;
    for (int kt = 0; kt < 8; ++kt) {
        int k0 = kt * 64;
        int kn = min(64, L_ - k0);
        for (int idx = tid; idx < 512; idx += 256) {
            int j = idx >> 3, d4 = (idx & 7) * 4;
            float4 v = make_float4(0.f, 0.f, 0.f, 0.f);
            if (j < kn) v = *(const float4*)(base + (size_t)(k0 + j) * 768 + 512 + h * 32 + d4);
            *(float4*)&Vs[j][d4] = v;
        }
        __syncthreads();

        int jmax = min(64, 460 - k0);
        for (int j4 = 0; j4 < jmax; j4 += 4) {
            float4 pa = *(const float4*)&Sc[2 * ri][k0 + j4];
            float4 pb = *(const float4*)&Sc[2 * ri + 1][k0 + j4];
#pragma unroll
            for (int u = 0; u < 4; ++u) {
                float pua = ((const float*)&pa)[u];
                float pub = ((const float*)&pb)[u];
                float2 v2 = *(const float2*)&Vs[j4 + u][c2];
                o00 += pua * v2.x; o01 += pua * v2.y;
                o10 += pub * v2.x; o11 += pub * v2.y;
            }
        }
        __syncthreads();
    }

    // store O
    {
        int i0 = 2 * ri, i1 = 2 * ri + 1;
        if (i0 < qn) {
            float2 r; r.x = o00; r.y = o01;
            *(float2*)(out + (size_t)(b * L_ + q0 + i0) * D_ + h * 32 + c2) = r;
        }
        if (i1 < qn) {
            float2 r; r.x = o10; r.y = o11;
            *(float2*)(out + (size_t)(b * L_ + q0 + i1) * D_ + h * 32 + c2) = r;
        }
    }
}

// ---------------------------------------------------------------------------
// Fused residual-add + LayerNorm: xout[row] = LN(res[row] + y[row]) * g + b
// One block per row, 256 threads = D.
// ---------------------------------------------------------------------------
__global__ __launch_bounds__(256) void ln_kernel(
    const float* __restrict__ res, const float* __restrict__ y,
    const float* __restrict__ g, const float* __restrict__ bb,
    float* __restrict__ xout)
{
    int row = blockIdx.x;
    int t = threadIdx.x;
    size_t off = (size_t)row * D_ + t;
    float v = res[off] + y[off];

    __shared__ float p1[4], p2[4];
    float sum = v;
#pragma unroll
    for (int o = 32; o > 0; o >>= 1) sum += __shfl_xor(sum, o);
    if ((t & 63) == 0) p1[t >> 6] = sum;
    __syncthreads();
    float mean = (p1[0] + p1[1] + p1[2] + p1[3]) * (1.0f / 256.0f);

    float d = v - mean;
    float sq = d * d;
#pragma unroll
    for (int o = 32; o > 0; o >>= 1) sq += __shfl_xor(sq, o);
    if ((t & 63) == 0) p2[t >> 6] = sq;
    __syncthreads();
    float var = (p2[0] + p2[1] + p2[2] + p2[3]) * (1.0f / 256.0f);
    float r = rsqrtf(var + 1e-5f);
    xout[off] = d * r * g[t] + bb[t];
}

// ---------------------------------------------------------------------------
// Head part 1: per token row -> scalar attention logit.
// 32 lanes per row (8 rows per block of 256).
// ---------------------------------------------------------------------------
__global__ __launch_bounds__(256) void head1_kernel(
    const float* __restrict__ X, const float* __restrict__ w1,
    const float* __restrict__ b1, const float* __restrict__ bng,
    const float* __restrict__ bnb, const float* __restrict__ w2,
    const float* __restrict__ b2, float* __restrict__ SCp)
{
    int row = blockIdx.x * 8 + (threadIdx.x >> 5);
    int j = threadIdx.x & 31;
    const float* x = X + (size_t)row * D_;
    float acc = 0.f;
    for (int d = 0; d < D_; ++d) acc += x[d] * w1[d * PH_ + j];
    acc += b1[j];
    float hb = acc * (bng[j] * rsqrtf(1.0f + 1e-5f)) + bnb[j];
    // gelu (tanh approximation, JAX default)
    const float c = 0.7978845608028654f;
    float t = tanhf(c * (hb + 0.044715f * hb * hb * hb));
    float gl = 0.5f * hb * (1.0f + t);
    float sp = gl * w2[j];
#pragma unroll
    for (int o = 16; o > 0; o >>= 1) sp += __shfl_xor(sp, o);
    if (j == 0) SCp[row] = sp + b2[0];
}

// ---------------------------------------------------------------------------
// Head part 2: softmax over L per batch + weighted pool over x.
// One block per b, 256 threads = D.
// ---------------------------------------------------------------------------
__global__ __launch_bounds__(256) void head2_kernel(
    const float* __restrict__ SCp, const float* __restrict__ X,
    float* __restrict__ outp)
{
    int b = blockIdx.x;
    int t = threadIdx.x;
    __shared__ float wbuf[L_];
    __shared__ float r1[4], r2[4];
    const float* s = SCp + (size_t)b * L_;

    float m = -1e30f;
    for (int j = t; j < L_; j += 256) m = fmaxf(m, s[j]);
#pragma unroll
    for (int o = 32; o > 0; o >>= 1) m = fmaxf(m, __shfl_xor(m, o));
    if ((t & 63) == 0) r1[t >> 6] = m;
    __syncthreads();
    m = fmaxf(fmaxf(r1[0], r1[1]), fmaxf(r1[2], r1[3]));

    float sum = 0.f;
    for (int j = t; j < L_; j += 256) {
        float e = expf(s[j] - m);
        wbuf[j] = e;
        sum += e;
    }
#pragma unroll
    for (int o = 32; o > 0; o >>= 1) sum += __shfl_xor(sum, o);
    if ((t & 63) == 0) r2[t >> 6] = sum;
    __syncthreads();
    sum = r2[0] + r2[1] + r2[2] + r2[3];
    float inv = 1.0f / sum;

    float acc = 0.f;
    const float* xb = X + (size_t)b * L_ * D_;
    for (int l = 0; l < L_; ++l) acc += wbuf[l] * xb[(size_t)l * D_ + t];
    outp[b * D_ + t] = acc * inv;
}

// ---------------------------------------------------------------------------
extern "C" void kernel_launch(void* const* d_in, const int* in_sizes, int n_in,
                              void* d_out, int out_size, void* d_ws, size_t ws_size,
                              hipStream_t stream)
{
    const float* gene   = (const float*)d_in[0];
    const float* coords = (const float*)d_in[1];
    const float* w_in   = (const float*)d_in[2];
    const float* b_in   = (const float*)d_in[3];
    const float* w_cls  = (const float*)d_in[4];
    const float* b_cls  = (const float*)d_in[5];
    const float* qkv_w  = (const float*)d_in[6];
    const float* qkv_b  = (const float*)d_in[7];
    const float* ln1_g  = (const float*)d_in[8];
    const float* ln1_b  = (const float*)d_in[9];
    const float* ffn_w1 = (const float*)d_in[10];
    const float* ffn_b1 = (const float*)d_in[11];
    const float* ffn_w2 = (const float*)d_in[12];
    const float* ffn_b2 = (const float*)d_in[13];
    const float* ln2_g  = (const float*)d_in[14];
    const float* ln2_b  = (const float*)d_in[15];
    const float* th1_w  = (const float*)d_in[16];
    const float* th1_b  = (const float*)d_in[17];
    const float* bn_g   = (const float*)d_in[18];
    const float* bn_b   = (const float*)d_in[19];
    const float* th2_w  = (const float*)d_in[20];
    const float* th2_b  = (const float*)d_in[21];
    float* out = (float*)d_out;
    float* ws = (float*)d_ws;

    const int ROWS = B_ * L_;           // 29248
    float* X   = ws;                    // 29248*256   = 7,487,488 floats
    float* QH  = X + (size_t)ROWS * D_; // max(29248*768, 29248*1024) floats
    float* TMP = QH + (size_t)ROWS * FF_;
    float* SCp = TMP + (size_t)ROWS * D_;

    // Embed: (B*NT,64) @ (64,256), row-remap to skip CLS slots
    sgemm_kernel<<<dim3(D_ / 64, (B_ * NT_) / 64), 256, 0, stream>>>(
        gene, w_in, b_in, X, B_ * NT_, D_, TOK_, 0, 1);
    cls_kernel<<<B_, 256, 0, stream>>>(coords, w_cls, b_cls, X);

    for (int l = 0; l < NL_; ++l) {
        sgemm_kernel<<<dim3(768 / 64, ROWS / 64), 256, 0, stream>>>(
            X, qkv_w + (size_t)l * D_ * 3 * D_, qkv_b + l * 3 * D_, QH,
            ROWS, 3 * D_, D_, 0, 0);
        attn_kernel<<<dim3(15, H_, B_), 256, 0, stream>>>(QH, TMP);
        ln_kernel<<<ROWS, 256, 0, stream>>>(X, TMP, ln1_g + l * D_, ln1_b + l * D_, X);
        sgemm_kernel<<<dim3(FF_ / 64, ROWS / 64), 256, 0, stream>>>(
            X, ffn_w1 + (size_t)l * D_ * FF_, ffn_b1 + l * FF_, QH,
            ROWS, FF_, D_, 1, 0);
        sgemm_kernel<<<dim3(D_ / 64, ROWS / 64), 256, 0, stream>>>(
            QH, ffn_w2 + (size_t)l * FF_ * D_, ffn_b2 + l * D_, TMP,
            ROWS, D_, FF_, 0, 0);
        ln_kernel<<<ROWS, 256, 0, stream>>>(X, TMP, ln2_g + l * D_, ln2_b + l * D_, X);
    }

    head1_kernel<<<ROWS / 8, 256, 0, stream>>>(
        X, th1_w, th1_b, bn_g, bn_b, th2_w, th2_b, SCp);
    head2_kernel<<<B_, 256, 0, stream>>>(SCp, X, out);
}

// Round 2
// 5213.547 us; speedup vs baseline: 1.5417x; 1.5417x over previous
//
#include <hip/hip_runtime.h>
#include <hip/hip_bf16.h>
#include <math.h>

#define B_   64
#define TOK_ 64
#define NT_  456
#define L_   457
#define D_   256
#define H_   8
#define HD_  32
#define FF_  1024
#define NL_  4
#define PH_  32

// ---------------------------------------------------------------------------
// Generic tiled SGEMM: C[M,N] = A[M,K] @ W[K,N] + bias, optional relu,
// optional embed row-remap (orow = row + row/456 + 1).
// Requires M%64==0, N%64==0, K%16==0.
// ---------------------------------------------------------------------------
__global__ __launch_bounds__(256) void sgemm_kernel(
    const float* __restrict__ A, const float* __restrict__ W,
    const float* __restrict__ bias, float* __restrict__ C,
    int M, int N, int K, int relu, int remap)
{
    __shared__ float As[16][64];
    __shared__ float Bs[16][64];
    int tid = threadIdx.x;
    int rowblk = blockIdx.y * 64;
    int colblk = blockIdx.x * 64;

    int a_row = tid & 63, a_q = tid >> 6;       // A loader: row, k-quad
    int b_kr  = tid >> 4, b_cg = tid & 15;      // B loader: k-row, col-group
    int rm = tid >> 4, cn = tid & 15;           // compute: 4 rows, 4 cols

    float acc[4][4] = {};
    const float* Aptr = A + (size_t)(rowblk + a_row) * K;

    for (int kt = 0; kt < K; kt += 16) {
        float4 av = *(const float4*)(Aptr + kt + a_q * 4);
        float4 bv = *(const float4*)(W + (size_t)(kt + b_kr) * N + colblk + b_cg * 4);
        As[a_q * 4 + 0][a_row] = av.x;
        As[a_q * 4 + 1][a_row] = av.y;
        As[a_q * 4 + 2][a_row] = av.z;
        As[a_q * 4 + 3][a_row] = av.w;
        *(float4*)&Bs[b_kr][b_cg * 4] = bv;
        __syncthreads();
#pragma unroll
        for (int kk = 0; kk < 16; ++kk) {
            float4 a4 = *(const float4*)&As[kk][rm * 4];
            float4 b4 = *(const float4*)&Bs[kk][cn * 4];
            float ar[4] = {a4.x, a4.y, a4.z, a4.w};
            float br[4] = {b4.x, b4.y, b4.z, b4.w};
#pragma unroll
            for (int i = 0; i < 4; ++i)
#pragma unroll
                for (int j = 0; j < 4; ++j)
                    acc[i][j] += ar[i] * br[j];
        }
        __syncthreads();
    }

    float4 bv = *(const float4*)(bias + colblk + cn * 4);
    float bb[4] = {bv.x, bv.y, bv.z, bv.w};
#pragma unroll
    for (int i = 0; i < 4; ++i) {
        int grow = rowblk + rm * 4 + i;
        size_t orow = remap ? (size_t)(grow + grow / NT_ + 1) : (size_t)grow;
        float4 r;
        float v0 = acc[i][0] + bb[0];
        float v1 = acc[i][1] + bb[1];
        float v2 = acc[i][2] + bb[2];
        float v3 = acc[i][3] + bb[3];
        if (relu) {
            v0 = fmaxf(v0, 0.f); v1 = fmaxf(v1, 0.f);
            v2 = fmaxf(v2, 0.f); v3 = fmaxf(v3, 0.f);
        }
        r.x = v0; r.y = v1; r.z = v2; r.w = v3;
        *(float4*)(C + orow * N + colblk + cn * 4) = r;
    }
}

// ---------------------------------------------------------------------------
// CLS row: X[b,0,:] = coords[b] @ w_cls + b_cls
// ---------------------------------------------------------------------------
__global__ __launch_bounds__(256) void cls_kernel(
    const float* __restrict__ coords, const float* __restrict__ w_cls,
    const float* __restrict__ b_cls, float* __restrict__ X)
{
    int b = blockIdx.x;
    int t = threadIdx.x;
    float c0 = coords[b * 3 + 0], c1 = coords[b * 3 + 1], c2 = coords[b * 3 + 2];
    X[(size_t)b * L_ * D_ + t] =
        c0 * w_cls[t] + c1 * w_cls[D_ + t] + c2 * w_cls[2 * D_ + t] + b_cls[t];
}

// ---------------------------------------------------------------------------
// Attention: per (b,h,qtile of 32 rows). Full score row in LDS, 2-pass.
// qkv layout per row: [q(256) | k(256) | v(256)], head h at offset h*32.
// LDS layout: Q/K/V tiles padded to 36 floats/row (144B: 16B-aligned rows,
// +4-bank rotation per row). K columns per lane are strided (cj + 16u) so
// the Ks b128 reads land 2-way per bank group (free) instead of 16-way.
// ---------------------------------------------------------------------------
__global__ __launch_bounds__(256) void attn_kernel(
    const float* __restrict__ qkv, float* __restrict__ out)
{
    int qt = blockIdx.x, h = blockIdx.y, b = blockIdx.z;
    __shared__ float Qs[32][36];
    __shared__ float Ks[64][36];
    __shared__ float Vs[64][36];
    __shared__ float Sc[32][460];

    int tid = threadIdx.x;
    int q0 = qt * 32;
    int qn = min(32, L_ - q0);
    const float scale = 0.17677669529663687f;  // 1/sqrt(32)
    float slope = (h < 4) ? 1.0f : 0.5f;
    const float* base = qkv + (size_t)b * L_ * 768;

    // Load Q tile (zero-fill beyond qn)
    {
        int i = tid >> 3, d4 = (tid & 7) * 4;
        float4 v = make_float4(0.f, 0.f, 0.f, 0.f);
        if (i < qn) v = *(const float4*)(base + (size_t)(q0 + i) * 768 + h * 32 + d4);
        *(float4*)&Qs[i][d4] = v;
    }

    int ri = tid >> 4;   // 0..15 -> rows 2ri, 2ri+1
    int cj = tid & 15;   // col group (strided: cols cj + 16u)

    // ---- pass 1: scores ----
    for (int kt = 0; kt < 8; ++kt) {
        int k0 = kt * 64;
        int kn = min(64, L_ - k0);
        for (int idx = tid; idx < 512; idx += 256) {
            int j = idx >> 3, d4 = (idx & 7) * 4;
            float4 v = make_float4(0.f, 0.f, 0.f, 0.f);
            if (j < kn) v = *(const float4*)(base + (size_t)(k0 + j) * 768 + 256 + h * 32 + d4);
            *(float4*)&Ks[j][d4] = v;
        }
        __syncthreads();

        float s[2][4] = {};
#pragma unroll
        for (int d4 = 0; d4 < 32; d4 += 4) {
            float4 qa = *(const float4*)&Qs[2 * ri][d4];
            float4 qb = *(const float4*)&Qs[2 * ri + 1][d4];
#pragma unroll
            for (int u = 0; u < 4; ++u) {
                float4 kv = *(const float4*)&Ks[cj + 16 * u][d4];
                s[0][u] += qa.x * kv.x + qa.y * kv.y + qa.z * kv.z + qa.w * kv.w;
                s[1][u] += qb.x * kv.x + qb.y * kv.y + qb.z * kv.z + qb.w * kv.w;
            }
        }
#pragma unroll
        for (int r = 0; r < 2; ++r) {
            int i = 2 * ri + r;
            int qpos = q0 + i;
#pragma unroll
            for (int u = 0; u < 4; ++u) {
                int jg = k0 + cj + 16 * u;
                if (jg < L_) {
                    float val = s[r][u] * scale - slope * fabsf((float)(qpos - jg));
                    Sc[i][jg] = val;
                }
            }
        }
        __syncthreads();
    }

    // zero the 457..459 pad (read by float4 in PV)
    if (tid < 32 * 3) {
        int i = tid / 3, p = tid % 3;
        Sc[i][L_ + p] = 0.f;
    }

    // ---- softmax per row (8 lanes per row) ----
    {
        int i = tid >> 3, g = tid & 7;
        if (i < qn) {
            float m = -1e30f;
            for (int j = g; j < L_; j += 8) m = fmaxf(m, Sc[i][j]);
#pragma unroll
            for (int o = 1; o < 8; o <<= 1) m = fmaxf(m, __shfl_xor(m, o));
            float sum = 0.f;
            for (int j = g; j < L_; j += 8) {
                float e = expf(Sc[i][j] - m);
                Sc[i][j] = e;
                sum += e;
            }
#pragma unroll
            for (int o = 1; o < 8; o <<= 1) sum += __shfl_xor(sum, o);
            float inv = 1.0f / sum;
            for (int j = g; j < L_; j += 8) Sc[i][j] *= inv;
        }
    }
    __syncthreads();

    // ---- pass 2: P @ V ----
    float o00 = 0.f, o01 = 0.f, o10 = 0.f, o11 = 0.f;
    int c2 = 2 * cj;
    for (int kt = 0; kt < 8; ++kt) {
        int k0 = kt * 64;
        int kn = min(64, L_ - k0);
        for (int idx = tid; idx < 512; idx += 256) {
            int j = idx >> 3, d4 = (idx & 7) * 4;
            float4 v = make_float4(0.f, 0.f, 0.f, 0.f);
            if (j < kn) v = *(const float4*)(base + (size_t)(k0 + j) * 768 + 512 + h * 32 + d4);
            *(float4*)&Vs[j][d4] = v;
        }
        __syncthreads();

        int jmax = min(64, 460 - k0);
        for (int j4 = 0; j4 < jmax; j4 += 4) {
            float4 pa = *(const float4*)&Sc[2 * ri][k0 + j4];
            float4 pb = *(const float4*)&Sc[2 * ri + 1][k0 + j4];
#pragma unroll
            for (int u = 0; u < 4; ++u) {
                float pua = ((const float*)&pa)[u];
                float pub = ((const float*)&pb)[u];
                float2 v2 = *(const float2*)&Vs[j4 + u][c2];
                o00 += pua * v2.x; o01 += pua * v2.y;
                o10 += pub * v2.x; o11 += pub * v2.y;
            }
        }
        __syncthreads();
    }

    // store O
    {
        int i0 = 2 * ri, i1 = 2 * ri + 1;
        if (i0 < qn) {
            float2 r; r.x = o00; r.y = o01;
            *(float2*)(out + (size_t)(b * L_ + q0 + i0) * D_ + h * 32 + c2) = r;
        }
        if (i1 < qn) {
            float2 r; r.x = o10; r.y = o11;
            *(float2*)(out + (size_t)(b * L_ + q0 + i1) * D_ + h * 32 + c2) = r;
        }
    }
}

// ---------------------------------------------------------------------------
// Fused residual-add + LayerNorm: xout[row] = LN(res[row] + y[row]) * g + b
// One block per row, 256 threads = D.
// ---------------------------------------------------------------------------
__global__ __launch_bounds__(256) void ln_kernel(
    const float* __restrict__ res, const float* __restrict__ y,
    const float* __restrict__ g, const float* __restrict__ bb,
    float* __restrict__ xout)
{
    int row = blockIdx.x;
    int t = threadIdx.x;
    size_t off = (size_t)row * D_ + t;
    float v = res[off] + y[off];

    __shared__ float p1[4], p2[4];
    float sum = v;
#pragma unroll
    for (int o = 32; o > 0; o >>= 1) sum += __shfl_xor(sum, o);
    if ((t & 63) == 0) p1[t >> 6] = sum;
    __syncthreads();
    float mean = (p1[0] + p1[1] + p1[2] + p1[3]) * (1.0f / 256.0f);

    float d = v - mean;
    float sq = d * d;
#pragma unroll
    for (int o = 32; o > 0; o >>= 1) sq += __shfl_xor(sq, o);
    if ((t & 63) == 0) p2[t >> 6] = sq;
    __syncthreads();
    float var = (p2[0] + p2[1] + p2[2] + p2[3]) * (1.0f / 256.0f);
    float r = rsqrtf(var + 1e-5f);
    xout[off] = d * r * g[t] + bb[t];
}

// ---------------------------------------------------------------------------
// Head part 1: per token row -> scalar attention logit.
// 32 lanes per row (8 rows per block of 256).
// ---------------------------------------------------------------------------
__global__ __launch_bounds__(256) void head1_kernel(
    const float* __restrict__ X, const float* __restrict__ w1,
    const float* __restrict__ b1, const float* __restrict__ bng,
    const float* __restrict__ bnb, const float* __restrict__ w2,
    const float* __restrict__ b2, float* __restrict__ SCp)
{
    int row = blockIdx.x * 8 + (threadIdx.x >> 5);
    int j = threadIdx.x & 31;
    const float* x = X + (size_t)row * D_;
    float acc = 0.f;
    for (int d = 0; d < D_; ++d) acc += x[d] * w1[d * PH_ + j];
    acc += b1[j];
    float hb = acc * (bng[j] * rsqrtf(1.0f + 1e-5f)) + bnb[j];
    // gelu (tanh approximation, JAX default)
    const float c = 0.7978845608028654f;
    float t = tanhf(c * (hb + 0.044715f * hb * hb * hb));
    float gl = 0.5f * hb * (1.0f + t);
    float sp = gl * w2[j];
#pragma unroll
    for (int o = 16; o > 0; o >>= 1) sp += __shfl_xor(sp, o);
    if (j == 0) SCp[row] = sp + b2[0];
}

// ---------------------------------------------------------------------------
// Head part 2: softmax over L per batch + weighted pool over x.
// One block per b, 256 threads = D.
// ---------------------------------------------------------------------------
__global__ __launch_bounds__(256) void head2_kernel(
    const float* __restrict__ SCp, const float* __restrict__ X,
    float* __restrict__ outp)
{
    int b = blockIdx.x;
    int t = threadIdx.x;
    __shared__ float wbuf[L_];
    __shared__ float r1[4], r2[4];
    const float* s = SCp + (size_t)b * L_;

    float m = -1e30f;
    for (int j = t; j < L_; j += 256) m = fmaxf(m, s[j]);
#pragma unroll
    for (int o = 32; o > 0; o >>= 1) m = fmaxf(m, __shfl_xor(m, o));
    if ((t & 63) == 0) r1[t >> 6] = m;
    __syncthreads();
    m = fmaxf(fmaxf(r1[0], r1[1]), fmaxf(r1[2], r1[3]));

    float sum = 0.f;
    for (int j = t; j < L_; j += 256) {
        float e = expf(s[j] - m);
        wbuf[j] = e;
        sum += e;
    }
#pragma unroll
    for (int o = 32; o > 0; o >>= 1) sum += __shfl_xor(sum, o);
    if ((t & 63) == 0) r2[t >> 6] = sum;
    __syncthreads();
    sum = r2[0] + r2[1] + r2[2] + r2[3];
    float inv = 1.0f / sum;

    float acc = 0.f;
    const float* xb = X + (size_t)b * L_ * D_;
    for (int l = 0; l < L_; ++l) acc += wbuf[l] * xb[(size_t)l * D_ + t];
    outp[b * D_ + t] = acc * inv;
}

// ---------------------------------------------------------------------------
extern "C" void kernel_launch(void* const* d_in, const int* in_sizes, int n_in,
                              void* d_out, int out_size, void* d_ws, size_t ws_size,
                              hipStream_t stream)
{
    const float* gene   = (const float*)d_in[0];
    const float* coords = (const float*)d_in[1];
    const float* w_in   = (const float*)d_in[2];
    const float* b_in   = (const float*)d_in[3];
    const float* w_cls  = (const float*)d_in[4];
    const float* b_cls  = (const float*)d_in[5];
    const float* qkv_w  = (const float*)d_in[6];
    const float* qkv_b  = (const float*)d_in[7];
    const float* ln1_g  = (const float*)d_in[8];
    const float* ln1_b  = (const float*)d_in[9];
    const float* ffn_w1 = (const float*)d_in[10];
    const float* ffn_b1 = (const float*)d_in[11];
    const float* ffn_w2 = (const float*)d_in[12];
    const float* ffn_b2 = (const float*)d_in[13];
    const float* ln2_g  = (const float*)d_in[14];
    const float* ln2_b  = (const float*)d_in[15];
    const float* th1_w  = (const float*)d_in[16];
    const float* th1_b  = (const float*)d_in[17];
    const float* bn_g   = (const float*)d_in[18];
    const float* bn_b   = (const float*)d_in[19];
    const float* th2_w  = (const float*)d_in[20];
    const float* th2_b  = (const float*)d_in[21];
    float* out = (float*)d_out;
    float* ws = (float*)d_ws;

    const int ROWS = B_ * L_;           // 29248
    float* X   = ws;                    // 29248*256   = 7,487,488 floats
    float* QH  = X + (size_t)ROWS * D_; // max(29248*768, 29248*1024) floats
    float* TMP = QH + (size_t)ROWS * FF_;
    float* SCp = TMP + (size_t)ROWS * D_;

    // Embed: (B*NT,64) @ (64,256), row-remap to skip CLS slots
    sgemm_kernel<<<dim3(D_ / 64, (B_ * NT_) / 64), 256, 0, stream>>>(
        gene, w_in, b_in, X, B_ * NT_, D_, TOK_, 0, 1);
    cls_kernel<<<B_, 256, 0, stream>>>(coords, w_cls, b_cls, X);

    for (int l = 0; l < NL_; ++l) {
        sgemm_kernel<<<dim3(768 / 64, ROWS / 64), 256, 0, stream>>>(
            X, qkv_w + (size_t)l * D_ * 3 * D_, qkv_b + l * 3 * D_, QH,
            ROWS, 3 * D_, D_, 0, 0);
        attn_kernel<<<dim3(15, H_, B_), 256, 0, stream>>>(QH, TMP);
        ln_kernel<<<ROWS, 256, 0, stream>>>(X, TMP, ln1_g + l * D_, ln1_b + l * D_, X);
        sgemm_kernel<<<dim3(FF_ / 64, ROWS / 64), 256, 0, stream>>>(
            X, ffn_w1 + (size_t)l * D_ * FF_, ffn_b1 + l * FF_, QH,
            ROWS, FF_, D_, 1, 0);
        sgemm_kernel<<<dim3(D_ / 64, ROWS / 64), 256, 0, stream>>>(
            QH, ffn_w2 + (size_t)l * FF_ * D_, ffn_b2 + l * D_, TMP,
            ROWS, D_, FF_, 0, 0);
        ln_kernel<<<ROWS, 256, 0, stream>>>(X, TMP, ln2_g + l * D_, ln2_b + l * D_, X);
    }

    head1_kernel<<<ROWS / 8, 256, 0, stream>>>(
        X, th1_w, th1_b, bn_g, bn_b, th2_w, th2_b, SCp);
    head2_kernel<<<B_, 256, 0, stream>>>(SCp, X, out);
}

// Round 3
// 2810.415 us; speedup vs baseline: 2.8599x; 1.8551x over previous
//
#include <hip/hip_runtime.h>
#include <math.h>

#define B_   64
#define TOK_ 64
#define NT_  456
#define L_   457
#define D_   256
#define H_   8
#define HD_  32
#define FF_  1024
#define NL_  4
#define PH_  32
#define MPAD 29312   // 229 * 128 (rows padded for 128-row GEMM tiles)

typedef unsigned int uint;
typedef unsigned short ushort;
typedef __bf16 v8bf __attribute__((ext_vector_type(8)));
typedef float v4f __attribute__((ext_vector_type(4)));

__device__ __forceinline__ float b2f_lo(uint x) { return __uint_as_float(x << 16); }
__device__ __forceinline__ float b2f_hi(uint x) { return __uint_as_float(x & 0xffff0000u); }
__device__ __forceinline__ ushort f2bu(float f) {
    union { float f; uint u; } x; x.f = f;
    uint r = (x.u + 0x7fffu + ((x.u >> 16) & 1u)) >> 16;
    return (ushort)r;
}

// async global->LDS 16B copy; lds base must be wave-uniform, data lands at
// base + lane*16 (m104/m108 semantics). Pointer casts via integer (CK trick).
__device__ __forceinline__ void gload16(const void* g, void* l) {
    __builtin_amdgcn_global_load_lds(
        (const __attribute__((address_space(1))) void*)(unsigned long long)(uintptr_t)g,
        (__attribute__((address_space(3))) void*)(uint)(uintptr_t)l,
        16, 0, 0);
}

// ---------------------------------------------------------------------------
// bf16 MFMA GEMM (m97 structure): C[M,N] = A[M,K]·W^T[N,K] + bias.
// 128x128 tile, BK=32, 4 waves (2x2), each wave 4x4 MFMA tiles of 16x16x32.
// XOR-swizzled k-granules so frag ds_read_b128 spreads over 8 bank groups.
// Grid: (N/128, M/128). A,WT bf16; C fp32 or bf16 (+optional relu).
// ---------------------------------------------------------------------------
__global__ __launch_bounds__(256) void mfma_gemm(
    const ushort* __restrict__ A, const ushort* __restrict__ WT,
    const float* __restrict__ bias, void* __restrict__ Cout,
    int N, int K, int relu, int obf16)
{
    __shared__ ushort As[128 * 32];
    __shared__ ushort Bs[128 * 32];
    int tid = threadIdx.x;
    int wave = tid >> 6, lane = tid & 63;
    int colblk = blockIdx.x * 128;
    int rowblk = blockIdx.y * 128;
    int wm = wave >> 1, wn = wave & 1;

    v4f acc[4][4];
#pragma unroll
    for (int i = 0; i < 4; ++i)
#pragma unroll
        for (int j = 0; j < 4; ++j) acc[i][j] = (v4f)0.0f;

    int fr = lane & 15, fq = lane >> 4;
    int scol = fq ^ (lane & 3) ^ ((lane >> 2) & 1);   // swizzled granule col

    // staging source chunks for this lane (2 passes of 256 granules)
    int c0 = wave * 64 + lane;
    int r0 = c0 >> 2, k0g = (c0 & 3) ^ (r0 & 3) ^ ((r0 >> 2) & 1);
    int c1 = 256 + c0;
    int r1 = c1 >> 2, k1g = (c1 & 3) ^ (r1 & 3) ^ ((r1 >> 2) & 1);

    const ushort* Ag0 = A + (size_t)(rowblk + r0) * K + k0g * 8;
    const ushort* Ag1 = A + (size_t)(rowblk + r1) * K + k1g * 8;
    const ushort* Bg0 = WT + (size_t)(colblk + r0) * K + k0g * 8;
    const ushort* Bg1 = WT + (size_t)(colblk + r1) * K + k1g * 8;
    ushort* lA0 = As + (size_t)(wave * 64) * 8;
    ushort* lA1 = As + (size_t)(256 + wave * 64) * 8;
    ushort* lB0 = Bs + (size_t)(wave * 64) * 8;
    ushort* lB1 = Bs + (size_t)(256 + wave * 64) * 8;

    for (int kt = 0; kt < K; kt += 32) {
        gload16(Ag0 + kt, lA0);
        gload16(Ag1 + kt, lA1);
        gload16(Bg0 + kt, lB0);
        gload16(Bg1 + kt, lB1);
        __syncthreads();

        v8bf a[4], b[4];
#pragma unroll
        for (int mi = 0; mi < 4; ++mi)
            a[mi] = *(const v8bf*)(As + (size_t)(wm * 64 + mi * 16 + fr) * 32 + scol * 8);
#pragma unroll
        for (int ni = 0; ni < 4; ++ni)
            b[ni] = *(const v8bf*)(Bs + (size_t)(wn * 64 + ni * 16 + fr) * 32 + scol * 8);
#pragma unroll
        for (int mi = 0; mi < 4; ++mi)
#pragma unroll
            for (int ni = 0; ni < 4; ++ni)
                acc[mi][ni] = __builtin_amdgcn_mfma_f32_16x16x32_bf16(
                    a[mi], b[ni], acc[mi][ni], 0, 0, 0);
        __syncthreads();
    }

    // epilogue: C/D layout col=lane&15, row=(lane>>4)*4+reg (m89/m91 verified)
#pragma unroll
    for (int ni = 0; ni < 4; ++ni) {
        int col = colblk + wn * 64 + ni * 16 + fr;
        float bv = bias[col];
#pragma unroll
        for (int mi = 0; mi < 4; ++mi) {
            int row = rowblk + wm * 64 + mi * 16 + fq * 4;
#pragma unroll
            for (int r = 0; r < 4; ++r) {
                float v = acc[mi][ni][r] + bv;
                if (relu) v = fmaxf(v, 0.f);
                if (obf16)
                    ((ushort*)Cout)[(size_t)(row + r) * N + col] = f2bu(v);
                else
                    ((float*)Cout)[(size_t)(row + r) * N + col] = v;
            }
        }
    }
}

// ---------------------------------------------------------------------------
// Weight transpose+cast: W[K,N] fp32 -> WT[N,K] bf16, per layer (blockIdx.z).
// ---------------------------------------------------------------------------
__global__ __launch_bounds__(256) void wcast_kernel(
    const float* __restrict__ W, ushort* __restrict__ WT, int K, int N)
{
    __shared__ float t[32][33];
    const float* Wl = W + (size_t)blockIdx.z * K * N;
    ushort* WTl = WT + (size_t)blockIdx.z * K * N;
    int n0 = blockIdx.x * 32, k0 = blockIdx.y * 32;
    int tx = threadIdx.x, ty = threadIdx.y;
#pragma unroll
    for (int r = 0; r < 32; r += 8)
        t[ty + r][tx] = Wl[(size_t)(k0 + ty + r) * N + n0 + tx];
    __syncthreads();
#pragma unroll
    for (int r = 0; r < 32; r += 8)
        WTl[(size_t)(n0 + ty + r) * K + k0 + tx] = f2bu(t[tx][ty + r]);
}

// fp32 -> bf16 bulk cast (X -> Xb), 4 elems/thread
__global__ __launch_bounds__(256) void castx_kernel(
    const float* __restrict__ X, ushort* __restrict__ Xb)
{
    int i = blockIdx.x * 256 + threadIdx.x;
    float4 v = ((const float4*)X)[i];
    ushort4 o;
    o.x = f2bu(v.x); o.y = f2bu(v.y); o.z = f2bu(v.z); o.w = f2bu(v.w);
    ((ushort4*)Xb)[i] = o;
}

// ---------------------------------------------------------------------------
// fp32 SGEMM for the tiny embed GEMM only (M=29184, N=256, K=64), row-remap.
// ---------------------------------------------------------------------------
__global__ __launch_bounds__(256) void sgemm_kernel(
    const float* __restrict__ A, const float* __restrict__ W,
    const float* __restrict__ bias, float* __restrict__ C,
    int M, int N, int K)
{
    __shared__ float As_[16][64];
    __shared__ float Bs_[16][64];
    int tid = threadIdx.x;
    int rowblk = blockIdx.y * 64;
    int colblk = blockIdx.x * 64;
    int a_row = tid & 63, a_q = tid >> 6;
    int b_kr = tid >> 4, b_cg = tid & 15;
    int rm = tid >> 4, cn = tid & 15;
    float acc[4][4] = {};
    const float* Aptr = A + (size_t)(rowblk + a_row) * K;
    for (int kt = 0; kt < K; kt += 16) {
        float4 av = *(const float4*)(Aptr + kt + a_q * 4);
        float4 bv = *(const float4*)(W + (size_t)(kt + b_kr) * N + colblk + b_cg * 4);
        As_[a_q * 4 + 0][a_row] = av.x;
        As_[a_q * 4 + 1][a_row] = av.y;
        As_[a_q * 4 + 2][a_row] = av.z;
        As_[a_q * 4 + 3][a_row] = av.w;
        *(float4*)&Bs_[b_kr][b_cg * 4] = bv;
        __syncthreads();
#pragma unroll
        for (int kk = 0; kk < 16; ++kk) {
            float4 a4 = *(const float4*)&As_[kk][rm * 4];
            float4 b4 = *(const float4*)&Bs_[kk][cn * 4];
            float ar[4] = {a4.x, a4.y, a4.z, a4.w};
            float br[4] = {b4.x, b4.y, b4.z, b4.w};
#pragma unroll
            for (int i = 0; i < 4; ++i)
#pragma unroll
                for (int j = 0; j < 4; ++j) acc[i][j] += ar[i] * br[j];
        }
        __syncthreads();
    }
    float4 bv = *(const float4*)(bias + colblk + cn * 4);
    float bb[4] = {bv.x, bv.y, bv.z, bv.w};
#pragma unroll
    for (int i = 0; i < 4; ++i) {
        int grow = rowblk + rm * 4 + i;
        size_t orow = (size_t)(grow + grow / NT_ + 1);   // skip CLS slots
        float4 r;
        r.x = acc[i][0] + bb[0]; r.y = acc[i][1] + bb[1];
        r.z = acc[i][2] + bb[2]; r.w = acc[i][3] + bb[3];
        *(float4*)(C + orow * N + colblk + cn * 4) = r;
    }
}

__global__ __launch_bounds__(256) void cls_kernel(
    const float* __restrict__ coords, const float* __restrict__ w_cls,
    const float* __restrict__ b_cls, float* __restrict__ X)
{
    int b = blockIdx.x;
    int t = threadIdx.x;
    float c0 = coords[b * 3 + 0], c1 = coords[b * 3 + 1], c2 = coords[b * 3 + 2];
    X[(size_t)b * L_ * D_ + t] =
        c0 * w_cls[t] + c1 * w_cls[D_ + t] + c2 * w_cls[2 * D_ + t] + b_cls[t];
}

// ---------------------------------------------------------------------------
// Attention (reads bf16 QKV): per (b,h,qtile of 32 rows). Padded fp32 LDS.
// ---------------------------------------------------------------------------
__global__ __launch_bounds__(256) void attn_kernel(
    const ushort* __restrict__ qkv, float* __restrict__ out)
{
    int qt = blockIdx.x, h = blockIdx.y, b = blockIdx.z;
    __shared__ float Qs[32][36];
    __shared__ float Ks[64][36];
    __shared__ float Vs[64][36];
    __shared__ float Sc[32][460];

    int tid = threadIdx.x;
    int q0 = qt * 32;
    int qn = min(32, L_ - q0);
    const float scale = 0.17677669529663687f;
    float slope = (h < 4) ? 1.0f : 0.5f;
    const ushort* base = qkv + (size_t)b * L_ * 768;

    if (tid < 128) {
        int i = tid >> 2, c8 = (tid & 3) * 8;
        float4 f0 = make_float4(0.f, 0.f, 0.f, 0.f), f1 = f0;
        if (i < qn) {
            uint4 u = *(const uint4*)(base + (size_t)(q0 + i) * 768 + h * 32 + c8);
            f0.x = b2f_lo(u.x); f0.y = b2f_hi(u.x);
            f0.z = b2f_lo(u.y); f0.w = b2f_hi(u.y);
            f1.x = b2f_lo(u.z); f1.y = b2f_hi(u.z);
            f1.z = b2f_lo(u.w); f1.w = b2f_hi(u.w);
        }
        *(float4*)&Qs[i][c8] = f0;
        *(float4*)&Qs[i][c8 + 4] = f1;
    }

    int ri = tid >> 4;
    int cj = tid & 15;

    // ---- pass 1: scores ----
    for (int kt = 0; kt < 8; ++kt) {
        int k0 = kt * 64;
        int kn = min(64, L_ - k0);
        {
            int j = tid >> 2, c8 = (tid & 3) * 8;
            float4 f0 = make_float4(0.f, 0.f, 0.f, 0.f), f1 = f0;
            if (j < kn) {
                uint4 u = *(const uint4*)(base + (size_t)(k0 + j) * 768 + 256 + h * 32 + c8);
                f0.x = b2f_lo(u.x); f0.y = b2f_hi(u.x);
                f0.z = b2f_lo(u.y); f0.w = b2f_hi(u.y);
                f1.x = b2f_lo(u.z); f1.y = b2f_hi(u.z);
                f1.z = b2f_lo(u.w); f1.w = b2f_hi(u.w);
            }
            *(float4*)&Ks[j][c8] = f0;
            *(float4*)&Ks[j][c8 + 4] = f1;
        }
        __syncthreads();

        float s[2][4] = {};
#pragma unroll
        for (int d4 = 0; d4 < 32; d4 += 4) {
            float4 qa = *(const float4*)&Qs[2 * ri][d4];
            float4 qb = *(const float4*)&Qs[2 * ri + 1][d4];
#pragma unroll
            for (int u = 0; u < 4; ++u) {
                float4 kv = *(const float4*)&Ks[cj + 16 * u][d4];
                s[0][u] += qa.x * kv.x + qa.y * kv.y + qa.z * kv.z + qa.w * kv.w;
                s[1][u] += qb.x * kv.x + qb.y * kv.y + qb.z * kv.z + qb.w * kv.w;
            }
        }
#pragma unroll
        for (int r = 0; r < 2; ++r) {
            int i = 2 * ri + r;
            int qpos = q0 + i;
#pragma unroll
            for (int u = 0; u < 4; ++u) {
                int jg = k0 + cj + 16 * u;
                if (jg < L_)
                    Sc[i][jg] = s[r][u] * scale - slope * fabsf((float)(qpos - jg));
            }
        }
        __syncthreads();
    }

    if (tid < 32 * 3) {
        int i = tid / 3, pp = tid % 3;
        Sc[i][L_ + pp] = 0.f;
    }

    // ---- softmax ----
    {
        int i = tid >> 3, g = tid & 7;
        if (i < qn) {
            float m = -1e30f;
            for (int j = g; j < L_; j += 8) m = fmaxf(m, Sc[i][j]);
#pragma unroll
            for (int o = 1; o < 8; o <<= 1) m = fmaxf(m, __shfl_xor(m, o));
            float sum = 0.f;
            for (int j = g; j < L_; j += 8) {
                float e = expf(Sc[i][j] - m);
                Sc[i][j] = e;
                sum += e;
            }
#pragma unroll
            for (int o = 1; o < 8; o <<= 1) sum += __shfl_xor(sum, o);
            float inv = 1.0f / sum;
            for (int j = g; j < L_; j += 8) Sc[i][j] *= inv;
        }
    }
    __syncthreads();

    // ---- pass 2: P @ V ----
    float o00 = 0.f, o01 = 0.f, o10 = 0.f, o11 = 0.f;
    int c2 = 2 * cj;
    for (int kt = 0; kt < 8; ++kt) {
        int k0 = kt * 64;
        int kn = min(64, L_ - k0);
        {
            int j = tid >> 2, c8 = (tid & 3) * 8;
            float4 f0 = make_float4(0.f, 0.f, 0.f, 0.f), f1 = f0;
            if (j < kn) {
                uint4 u = *(const uint4*)(base + (size_t)(k0 + j) * 768 + 512 + h * 32 + c8);
                f0.x = b2f_lo(u.x); f0.y = b2f_hi(u.x);
                f0.z = b2f_lo(u.y); f0.w = b2f_hi(u.y);
                f1.x = b2f_lo(u.z); f1.y = b2f_hi(u.z);
                f1.z = b2f_lo(u.w); f1.w = b2f_hi(u.w);
            }
            *(float4*)&Vs[j][c8] = f0;
            *(float4*)&Vs[j][c8 + 4] = f1;
        }
        __syncthreads();

        int jmax = min(64, 460 - k0);
        for (int j4 = 0; j4 < jmax; j4 += 4) {
            float4 pa = *(const float4*)&Sc[2 * ri][k0 + j4];
            float4 pb = *(const float4*)&Sc[2 * ri + 1][k0 + j4];
#pragma unroll
            for (int u = 0; u < 4; ++u) {
                float pua = ((const float*)&pa)[u];
                float pub = ((const float*)&pb)[u];
                float2 v2 = *(const float2*)&Vs[j4 + u][c2];
                o00 += pua * v2.x; o01 += pua * v2.y;
                o10 += pub * v2.x; o11 += pub * v2.y;
            }
        }
        __syncthreads();
    }

    {
        int i0 = 2 * ri, i1 = 2 * ri + 1;
        if (i0 < qn) {
            float2 r; r.x = o00; r.y = o01;
            *(float2*)(out + (size_t)(b * L_ + q0 + i0) * D_ + h * 32 + c2) = r;
        }
        if (i1 < qn) {
            float2 r; r.x = o10; r.y = o11;
            *(float2*)(out + (size_t)(b * L_ + q0 + i1) * D_ + h * 32 + c2) = r;
        }
    }
}

// ---------------------------------------------------------------------------
// Fused residual+LN; writes fp32 X and bf16 Xb.
// ---------------------------------------------------------------------------
__global__ __launch_bounds__(256) void ln_kernel(
    const float* __restrict__ res, const float* __restrict__ y,
    const float* __restrict__ g, const float* __restrict__ bb,
    float* __restrict__ xout, ushort* __restrict__ xbout)
{
    int row = blockIdx.x;
    int t = threadIdx.x;
    size_t off = (size_t)row * D_ + t;
    float v = res[off] + y[off];

    __shared__ float p1[4], p2[4];
    float sum = v;
#pragma unroll
    for (int o = 32; o > 0; o >>= 1) sum += __shfl_xor(sum, o);
    if ((t & 63) == 0) p1[t >> 6] = sum;
    __syncthreads();
    float mean = (p1[0] + p1[1] + p1[2] + p1[3]) * (1.0f / 256.0f);

    float d = v - mean;
    float sq = d * d;
#pragma unroll
    for (int o = 32; o > 0; o >>= 1) sq += __shfl_xor(sq, o);
    if ((t & 63) == 0) p2[t >> 6] = sq;
    __syncthreads();
    float var = (p2[0] + p2[1] + p2[2] + p2[3]) * (1.0f / 256.0f);
    float r = rsqrtf(var + 1e-5f);
    float o = d * r * g[t] + bb[t];
    xout[off] = o;
    xbout[off] = f2bu(o);
}

__global__ __launch_bounds__(256) void head1_kernel(
    const float* __restrict__ X, const float* __restrict__ w1,
    const float* __restrict__ b1, const float* __restrict__ bng,
    const float* __restrict__ bnb, const float* __restrict__ w2,
    const float* __restrict__ b2, float* __restrict__ SCp)
{
    int row = blockIdx.x * 8 + (threadIdx.x >> 5);
    int j = threadIdx.x & 31;
    const float* x = X + (size_t)row * D_;
    float acc = 0.f;
    for (int d = 0; d < D_; ++d) acc += x[d] * w1[d * PH_ + j];
    acc += b1[j];
    float hb = acc * (bng[j] * rsqrtf(1.0f + 1e-5f)) + bnb[j];
    const float c = 0.7978845608028654f;
    float t = tanhf(c * (hb + 0.044715f * hb * hb * hb));
    float gl = 0.5f * hb * (1.0f + t);
    float sp = gl * w2[j];
#pragma unroll
    for (int o = 16; o > 0; o >>= 1) sp += __shfl_xor(sp, o);
    if (j == 0) SCp[row] = sp + b2[0];
}

__global__ __launch_bounds__(256) void head2_kernel(
    const float* __restrict__ SCp, const float* __restrict__ X,
    float* __restrict__ outp)
{
    int b = blockIdx.x;
    int t = threadIdx.x;
    __shared__ float wbuf[L_];
    __shared__ float r1[4], r2[4];
    const float* s = SCp + (size_t)b * L_;

    float m = -1e30f;
    for (int j = t; j < L_; j += 256) m = fmaxf(m, s[j]);
#pragma unroll
    for (int o = 32; o > 0; o >>= 1) m = fmaxf(m, __shfl_xor(m, o));
    if ((t & 63) == 0) r1[t >> 6] = m;
    __syncthreads();
    m = fmaxf(fmaxf(r1[0], r1[1]), fmaxf(r1[2], r1[3]));

    float sum = 0.f;
    for (int j = t; j < L_; j += 256) {
        float e = expf(s[j] - m);
        wbuf[j] = e;
        sum += e;
    }
#pragma unroll
    for (int o = 32; o > 0; o >>= 1) sum += __shfl_xor(sum, o);
    if ((t & 63) == 0) r2[t >> 6] = sum;
    __syncthreads();
    sum = r2[0] + r2[1] + r2[2] + r2[3];
    float inv = 1.0f / sum;

    float acc = 0.f;
    const float* xb = X + (size_t)b * L_ * D_;
    for (int l = 0; l < L_; ++l) acc += wbuf[l] * xb[(size_t)l * D_ + t];
    outp[b * D_ + t] = acc * inv;
}

// ---------------------------------------------------------------------------
extern "C" void kernel_launch(void* const* d_in, const int* in_sizes, int n_in,
                              void* d_out, int out_size, void* d_ws, size_t ws_size,
                              hipStream_t stream)
{
    const float* gene   = (const float*)d_in[0];
    const float* coords = (const float*)d_in[1];
    const float* w_in   = (const float*)d_in[2];
    const float* b_in   = (const float*)d_in[3];
    const float* w_cls  = (const float*)d_in[4];
    const float* b_cls  = (const float*)d_in[5];
    const float* qkv_w  = (const float*)d_in[6];
    const float* qkv_b  = (const float*)d_in[7];
    const float* ln1_g  = (const float*)d_in[8];
    const float* ln1_b  = (const float*)d_in[9];
    const float* ffn_w1 = (const float*)d_in[10];
    const float* ffn_b1 = (const float*)d_in[11];
    const float* ffn_w2 = (const float*)d_in[12];
    const float* ffn_b2 = (const float*)d_in[13];
    const float* ln2_g  = (const float*)d_in[14];
    const float* ln2_b  = (const float*)d_in[15];
    const float* th1_w  = (const float*)d_in[16];
    const float* th1_b  = (const float*)d_in[17];
    const float* bn_g   = (const float*)d_in[18];
    const float* bn_b   = (const float*)d_in[19];
    const float* th2_w  = (const float*)d_in[20];
    const float* th2_b  = (const float*)d_in[21];
    float* out = (float*)d_out;

    const int ROWS = B_ * L_;   // 29248
    char* p = (char*)d_ws;
    float*  X    = (float*)p;  p += (size_t)MPAD * 256 * 4;   // fp32 residual
    float*  AO   = (float*)p;  p += (size_t)MPAD * 256 * 4;   // attn/ffn2 out
    ushort* Xb   = (ushort*)p; p += (size_t)MPAD * 256 * 2;   // bf16 activations
    ushort* SH   = (ushort*)p; p += (size_t)MPAD * 1024 * 2;  // QKV-out / FFN1-out (aliased)
    ushort* qkvT = (ushort*)p; p += (size_t)NL_ * 768 * 256 * 2;
    ushort* w1T  = (ushort*)p; p += (size_t)NL_ * 1024 * 256 * 2;
    ushort* w2T  = (ushort*)p; p += (size_t)NL_ * 256 * 1024 * 2;
    float*  SCp  = (float*)p;  p += (size_t)ROWS * 4;

    // weights -> bf16 transposed [N,K]
    wcast_kernel<<<dim3(768 / 32, 256 / 32, NL_), dim3(32, 8), 0, stream>>>(qkv_w, qkvT, 256, 768);
    wcast_kernel<<<dim3(1024 / 32, 256 / 32, NL_), dim3(32, 8), 0, stream>>>(ffn_w1, w1T, 256, 1024);
    wcast_kernel<<<dim3(256 / 32, 1024 / 32, NL_), dim3(32, 8), 0, stream>>>(ffn_w2, w2T, 1024, 256);

    // embed + CLS, then cast to bf16
    sgemm_kernel<<<dim3(D_ / 64, (B_ * NT_) / 64), 256, 0, stream>>>(
        gene, w_in, b_in, X, B_ * NT_, D_, TOK_);
    cls_kernel<<<B_, 256, 0, stream>>>(coords, w_cls, b_cls, X);
    castx_kernel<<<(MPAD * 256 / 4) / 256, 256, 0, stream>>>(X, Xb);

    for (int l = 0; l < NL_; ++l) {
        mfma_gemm<<<dim3(768 / 128, MPAD / 128), 256, 0, stream>>>(
            Xb, qkvT + (size_t)l * 768 * 256, qkv_b + l * 768, SH, 768, 256, 0, 1);
        attn_kernel<<<dim3(15, H_, B_), 256, 0, stream>>>(SH, AO);
        ln_kernel<<<ROWS, 256, 0, stream>>>(X, AO, ln1_g + l * D_, ln1_b + l * D_, X, Xb);
        mfma_gemm<<<dim3(1024 / 128, MPAD / 128), 256, 0, stream>>>(
            Xb, w1T + (size_t)l * 1024 * 256, ffn_b1 + l * 1024, SH, 1024, 256, 1, 1);
        mfma_gemm<<<dim3(256 / 128, MPAD / 128), 256, 0, stream>>>(
            SH, w2T + (size_t)l * 256 * 1024, ffn_b2 + l * D_, AO, 256, 1024, 0, 0);
        ln_kernel<<<ROWS, 256, 0, stream>>>(X, AO, ln2_g + l * D_, ln2_b + l * D_, X, Xb);
    }

    head1_kernel<<<ROWS / 8, 256, 0, stream>>>(
        X, th1_w, th1_b, bn_g, bn_b, th2_w, th2_b, SCp);
    head2_kernel<<<B_, 256, 0, stream>>>(SCp, X, out);
}

// Round 4
// 1650.953 us; speedup vs baseline: 4.8684x; 1.7023x over previous
//
#include <hip/hip_runtime.h>
#include <math.h>

#define B_   64
#define TOK_ 64
#define NT_  456
#define L_   457
#define D_   256
#define H_   8
#define HD_  32
#define FF_  1024
#define NL_  4
#define PH_  32
#define MPAD 29312   // 229 * 128 (rows padded for 128-row GEMM tiles)

typedef unsigned int uint;
typedef unsigned short ushort;
typedef __bf16 v8bf __attribute__((ext_vector_type(8)));
typedef float v4f __attribute__((ext_vector_type(4)));

__device__ __forceinline__ float bu2f(ushort x) {
    return __uint_as_float(((uint)x) << 16);
}
__device__ __forceinline__ ushort f2bu(float f) {
    union { float f; uint u; } x; x.f = f;
    uint r = (x.u + 0x7fffu + ((x.u >> 16) & 1u)) >> 16;
    return (ushort)r;
}

// async global->LDS 16B copy; lds base wave-uniform, data at base + lane*16.
__device__ __forceinline__ void gload16(const void* g, void* l) {
    __builtin_amdgcn_global_load_lds(
        (const __attribute__((address_space(1))) void*)(unsigned long long)(uintptr_t)g,
        (__attribute__((address_space(3))) void*)(uint)(uintptr_t)l,
        16, 0, 0);
}

// ---------------------------------------------------------------------------
// bf16 MFMA GEMM (m97 structure): C[M,N] = A[M,K]·W^T[N,K] + bias.
// ---------------------------------------------------------------------------
__global__ __launch_bounds__(256) void mfma_gemm(
    const ushort* __restrict__ A, const ushort* __restrict__ WT,
    const float* __restrict__ bias, void* __restrict__ Cout,
    int N, int K, int relu, int obf16)
{
    __shared__ ushort As[128 * 32];
    __shared__ ushort Bs[128 * 32];
    int tid = threadIdx.x;
    int wave = tid >> 6, lane = tid & 63;
    int colblk = blockIdx.x * 128;
    int rowblk = blockIdx.y * 128;
    int wm = wave >> 1, wn = wave & 1;

    v4f acc[4][4];
#pragma unroll
    for (int i = 0; i < 4; ++i)
#pragma unroll
        for (int j = 0; j < 4; ++j) acc[i][j] = (v4f)0.0f;

    int fr = lane & 15, fq = lane >> 4;
    int scol = fq ^ (lane & 3) ^ ((lane >> 2) & 1);

    int c0 = wave * 64 + lane;
    int r0 = c0 >> 2, k0g = (c0 & 3) ^ (r0 & 3) ^ ((r0 >> 2) & 1);
    int c1 = 256 + c0;
    int r1 = c1 >> 2, k1g = (c1 & 3) ^ (r1 & 3) ^ ((r1 >> 2) & 1);

    const ushort* Ag0 = A + (size_t)(rowblk + r0) * K + k0g * 8;
    const ushort* Ag1 = A + (size_t)(rowblk + r1) * K + k1g * 8;
    const ushort* Bg0 = WT + (size_t)(colblk + r0) * K + k0g * 8;
    const ushort* Bg1 = WT + (size_t)(colblk + r1) * K + k1g * 8;
    ushort* lA0 = As + (size_t)(wave * 64) * 8;
    ushort* lA1 = As + (size_t)(256 + wave * 64) * 8;
    ushort* lB0 = Bs + (size_t)(wave * 64) * 8;
    ushort* lB1 = Bs + (size_t)(256 + wave * 64) * 8;

    for (int kt = 0; kt < K; kt += 32) {
        gload16(Ag0 + kt, lA0);
        gload16(Ag1 + kt, lA1);
        gload16(Bg0 + kt, lB0);
        gload16(Bg1 + kt, lB1);
        __syncthreads();

        v8bf a[4], b[4];
#pragma unroll
        for (int mi = 0; mi < 4; ++mi)
            a[mi] = *(const v8bf*)(As + (size_t)(wm * 64 + mi * 16 + fr) * 32 + scol * 8);
#pragma unroll
        for (int ni = 0; ni < 4; ++ni)
            b[ni] = *(const v8bf*)(Bs + (size_t)(wn * 64 + ni * 16 + fr) * 32 + scol * 8);
#pragma unroll
        for (int mi = 0; mi < 4; ++mi)
#pragma unroll
            for (int ni = 0; ni < 4; ++ni)
                acc[mi][ni] = __builtin_amdgcn_mfma_f32_16x16x32_bf16(
                    a[mi], b[ni], acc[mi][ni], 0, 0, 0);
        __syncthreads();
    }

#pragma unroll
    for (int ni = 0; ni < 4; ++ni) {
        int col = colblk + wn * 64 + ni * 16 + fr;
        float bv = bias[col];
#pragma unroll
        for (int mi = 0; mi < 4; ++mi) {
            int row = rowblk + wm * 64 + mi * 16 + fq * 4;
#pragma unroll
            for (int r = 0; r < 4; ++r) {
                float v = acc[mi][ni][r] + bv;
                if (relu) v = fmaxf(v, 0.f);
                if (obf16)
                    ((ushort*)Cout)[(size_t)(row + r) * N + col] = f2bu(v);
                else
                    ((float*)Cout)[(size_t)(row + r) * N + col] = v;
            }
        }
    }
}

// ---------------------------------------------------------------------------
__global__ __launch_bounds__(256) void wcast_kernel(
    const float* __restrict__ W, ushort* __restrict__ WT, int K, int N)
{
    __shared__ float t[32][33];
    const float* Wl = W + (size_t)blockIdx.z * K * N;
    ushort* WTl = WT + (size_t)blockIdx.z * K * N;
    int n0 = blockIdx.x * 32, k0 = blockIdx.y * 32;
    int tx = threadIdx.x, ty = threadIdx.y;
#pragma unroll
    for (int r = 0; r < 32; r += 8)
        t[ty + r][tx] = Wl[(size_t)(k0 + ty + r) * N + n0 + tx];
    __syncthreads();
#pragma unroll
    for (int r = 0; r < 32; r += 8)
        WTl[(size_t)(n0 + ty + r) * K + k0 + tx] = f2bu(t[tx][ty + r]);
}

__global__ __launch_bounds__(256) void castx_kernel(
    const float* __restrict__ X, ushort* __restrict__ Xb)
{
    int i = blockIdx.x * 256 + threadIdx.x;
    float4 v = ((const float4*)X)[i];
    ushort4 o;
    o.x = f2bu(v.x); o.y = f2bu(v.y); o.z = f2bu(v.z); o.w = f2bu(v.w);
    ((ushort4*)Xb)[i] = o;
}

// ---------------------------------------------------------------------------
// fp32 SGEMM for the embed GEMM only (M=29184, N=256, K=64), row-remap.
// ---------------------------------------------------------------------------
__global__ __launch_bounds__(256) void sgemm_kernel(
    const float* __restrict__ A, const float* __restrict__ W,
    const float* __restrict__ bias, float* __restrict__ C,
    int M, int N, int K)
{
    __shared__ float As_[16][64];
    __shared__ float Bs_[16][64];
    int tid = threadIdx.x;
    int rowblk = blockIdx.y * 64;
    int colblk = blockIdx.x * 64;
    int a_row = tid & 63, a_q = tid >> 6;
    int b_kr = tid >> 4, b_cg = tid & 15;
    int rm = tid >> 4, cn = tid & 15;
    float acc[4][4] = {};
    const float* Aptr = A + (size_t)(rowblk + a_row) * K;
    for (int kt = 0; kt < K; kt += 16) {
        float4 av = *(const float4*)(Aptr + kt + a_q * 4);
        float4 bv = *(const float4*)(W + (size_t)(kt + b_kr) * N + colblk + b_cg * 4);
        As_[a_q * 4 + 0][a_row] = av.x;
        As_[a_q * 4 + 1][a_row] = av.y;
        As_[a_q * 4 + 2][a_row] = av.z;
        As_[a_q * 4 + 3][a_row] = av.w;
        *(float4*)&Bs_[b_kr][b_cg * 4] = bv;
        __syncthreads();
#pragma unroll
        for (int kk = 0; kk < 16; ++kk) {
            float4 a4 = *(const float4*)&As_[kk][rm * 4];
            float4 b4 = *(const float4*)&Bs_[kk][cn * 4];
            float ar[4] = {a4.x, a4.y, a4.z, a4.w};
            float br[4] = {b4.x, b4.y, b4.z, b4.w};
#pragma unroll
            for (int i = 0; i < 4; ++i)
#pragma unroll
                for (int j = 0; j < 4; ++j) acc[i][j] += ar[i] * br[j];
        }
        __syncthreads();
    }
    float4 bv = *(const float4*)(bias + colblk + cn * 4);
    float bb[4] = {bv.x, bv.y, bv.z, bv.w};
#pragma unroll
    for (int i = 0; i < 4; ++i) {
        int grow = rowblk + rm * 4 + i;
        size_t orow = (size_t)(grow + grow / NT_ + 1);
        float4 r;
        r.x = acc[i][0] + bb[0]; r.y = acc[i][1] + bb[1];
        r.z = acc[i][2] + bb[2]; r.w = acc[i][3] + bb[3];
        *(float4*)(C + orow * N + colblk + cn * 4) = r;
    }
}

__global__ __launch_bounds__(256) void cls_kernel(
    const float* __restrict__ coords, const float* __restrict__ w_cls,
    const float* __restrict__ b_cls, float* __restrict__ X)
{
    int b = blockIdx.x;
    int t = threadIdx.x;
    float c0 = coords[b * 3 + 0], c1 = coords[b * 3 + 1], c2 = coords[b * 3 + 2];
    X[(size_t)b * L_ * D_ + t] =
        c0 * w_cls[t] + c1 * w_cls[D_ + t] + c2 * w_cls[2 * D_ + t] + b_cls[t];
}

// ---------------------------------------------------------------------------
// MFMA attention: per (b,h,32-row qtile). QK^T and PV on matrix cores.
// Frag conventions identical to mfma_gemm (verified): A/B row-major [16][32],
// lane reads 16B at [lane&15][quad*8]; C/D col=lane&15, row=quad*4+reg.
// Scores in LDS as bf16 (scale applied; alibi bias re-added fp32 in softmax).
// LDS pitches: 80B/144B/976B rows -> 20/4/20-bank rotations (2-way, free).
// ---------------------------------------------------------------------------
__global__ __launch_bounds__(256) void attn_kernel(
    const ushort* __restrict__ qkv, float* __restrict__ out)
{
    int qt = blockIdx.x, h = blockIdx.y, b = blockIdx.z;
    __shared__ ushort Qs[32][40];
    __shared__ ushort Ks[64][40];
    __shared__ ushort Vt[32][72];
    __shared__ ushort Sc[32][488];
    __shared__ float lrow[32];

    int tid = threadIdx.x;
    int wave = tid >> 6, lane = tid & 63;
    int fr = lane & 15, fq = lane >> 4;
    int wm = wave >> 1, wn = wave & 1;
    int q0 = qt * 32;
    int qn = min(32, L_ - q0);
    const float scale = 0.17677669529663687f;
    float slope = (h < 4) ? 1.0f : 0.5f;
    const ushort* base = qkv + (size_t)b * L_ * 768;

    // stage Q tile (zero-fill rows >= qn)
    {
        int i = tid >> 3, c4 = (tid & 7) * 4;
        uint2 u = make_uint2(0u, 0u);
        if (i < qn) u = *(const uint2*)(base + (size_t)(q0 + i) * 768 + h * 32 + c4);
        *(uint2*)&Qs[i][c4] = u;
    }
    __syncthreads();

    v8bf qfrag = *(const v8bf*)&Qs[wm * 16 + fr][fq * 8];

    // ---- QK^T ----
    for (int c = 0; c < 8; ++c) {
        int k0 = c * 64;
        int kn = min(64, L_ - k0);
        {
            int j = tid >> 2, c8 = (tid & 3) * 8;
            uint4 u = make_uint4(0u, 0u, 0u, 0u);
            if (j < kn) u = *(const uint4*)(base + (size_t)(k0 + j) * 768 + 256 + h * 32 + c8);
            *(uint4*)&Ks[j][c8] = u;
        }
        __syncthreads();
#pragma unroll
        for (int t = 0; t < 2; ++t) {
            int jt = wn + 2 * t;
            int col0 = k0 + jt * 16;
            if (col0 < L_) {
                v8bf bfrag = *(const v8bf*)&Ks[jt * 16 + fr][fq * 8];
                v4f d = (v4f)0.0f;
                d = __builtin_amdgcn_mfma_f32_16x16x32_bf16(qfrag, bfrag, d, 0, 0, 0);
                int col = col0 + fr;
                if (col < L_) {
#pragma unroll
                    for (int r = 0; r < 4; ++r)
                        Sc[wm * 16 + fq * 4 + r][col] = f2bu(d[r] * scale);
                }
            }
        }
        __syncthreads();
    }

    // ---- softmax (fp32 math, bias re-added here; P written bf16) ----
    {
        int i = tid >> 3, g = tid & 7;
        float ig = (float)(q0 + i);
        float m = -1e30f;
        for (int j = g; j < L_; j += 8) {
            float v = bu2f(Sc[i][j]) - slope * fabsf(ig - (float)j);
            m = fmaxf(m, v);
        }
#pragma unroll
        for (int o = 1; o < 8; o <<= 1) m = fmaxf(m, __shfl_xor(m, o));
        float sum = 0.f;
        for (int j = g; j < L_; j += 8) {
            float v = bu2f(Sc[i][j]) - slope * fabsf(ig - (float)j) - m;
            float e = __expf(v);
            sum += e;
            Sc[i][j] = f2bu(e);
        }
#pragma unroll
        for (int o = 1; o < 8; o <<= 1) sum += __shfl_xor(sum, o);
        if (g == 0) lrow[i] = sum;
        for (int j = L_ + g; j < 488; j += 8) Sc[i][j] = 0;
    }
    __syncthreads();

    // ---- P @ V ----
    v4f oacc = (v4f)0.0f;
    for (int c = 0; c < 8; ++c) {
        int k0 = c * 64;
        int kn = min(64, L_ - k0);
        {
            int j = tid >> 2, dg = (tid & 3) * 8;
            uint4 u = make_uint4(0u, 0u, 0u, 0u);
            if (j < kn) u = *(const uint4*)(base + (size_t)(k0 + j) * 768 + 512 + h * 32 + dg);
            const ushort* pu = (const ushort*)&u;
#pragma unroll
            for (int e = 0; e < 8; ++e) Vt[dg + e][j] = pu[e];
        }
        __syncthreads();
#pragma unroll
        for (int s = 0; s < 2; ++s) {
            int j0 = k0 + s * 32;
            if (j0 < L_) {
                v8bf pfrag = *(const v8bf*)&Sc[wm * 16 + fr][j0 + fq * 8];
                v8bf vfrag = *(const v8bf*)&Vt[wn * 16 + fr][s * 32 + fq * 8];
                oacc = __builtin_amdgcn_mfma_f32_16x16x32_bf16(pfrag, vfrag, oacc, 0, 0, 0);
            }
        }
        __syncthreads();
    }

    // epilogue: O row scaled by 1/l
#pragma unroll
    for (int r = 0; r < 4; ++r) {
        int row = wm * 16 + fq * 4 + r;
        if (row < qn) {
            float v = oacc[r] / lrow[row];
            out[(size_t)(b * L_ + q0 + row) * D_ + h * 32 + wn * 16 + fr] = v;
        }
    }
}

// ---------------------------------------------------------------------------
__global__ __launch_bounds__(256) void ln_kernel(
    const float* __restrict__ res, const float* __restrict__ y,
    const float* __restrict__ g, const float* __restrict__ bb,
    float* __restrict__ xout, ushort* __restrict__ xbout)
{
    int row = blockIdx.x;
    int t = threadIdx.x;
    size_t off = (size_t)row * D_ + t;
    float v = res[off] + y[off];

    __shared__ float p1[4], p2[4];
    float sum = v;
#pragma unroll
    for (int o = 32; o > 0; o >>= 1) sum += __shfl_xor(sum, o);
    if ((t & 63) == 0) p1[t >> 6] = sum;
    __syncthreads();
    float mean = (p1[0] + p1[1] + p1[2] + p1[3]) * (1.0f / 256.0f);

    float d = v - mean;
    float sq = d * d;
#pragma unroll
    for (int o = 32; o > 0; o >>= 1) sq += __shfl_xor(sq, o);
    if ((t & 63) == 0) p2[t >> 6] = sq;
    __syncthreads();
    float var = (p2[0] + p2[1] + p2[2] + p2[3]) * (1.0f / 256.0f);
    float r = rsqrtf(var + 1e-5f);
    float o = d * r * g[t] + bb[t];
    xout[off] = o;
    xbout[off] = f2bu(o);
}

__global__ __launch_bounds__(256) void head1_kernel(
    const float* __restrict__ X, const float* __restrict__ w1,
    const float* __restrict__ b1, const float* __restrict__ bng,
    const float* __restrict__ bnb, const float* __restrict__ w2,
    const float* __restrict__ b2, float* __restrict__ SCp)
{
    int row = blockIdx.x * 8 + (threadIdx.x >> 5);
    int j = threadIdx.x & 31;
    const float* x = X + (size_t)row * D_;
    float acc = 0.f;
    for (int d = 0; d < D_; ++d) acc += x[d] * w1[d * PH_ + j];
    acc += b1[j];
    float hb = acc * (bng[j] * rsqrtf(1.0f + 1e-5f)) + bnb[j];
    const float c = 0.7978845608028654f;
    float t = tanhf(c * (hb + 0.044715f * hb * hb * hb));
    float gl = 0.5f * hb * (1.0f + t);
    float sp = gl * w2[j];
#pragma unroll
    for (int o = 16; o > 0; o >>= 1) sp += __shfl_xor(sp, o);
    if (j == 0) SCp[row] = sp + b2[0];
}

__global__ __launch_bounds__(256) void head2_kernel(
    const float* __restrict__ SCp, const float* __restrict__ X,
    float* __restrict__ outp)
{
    int b = blockIdx.x;
    int t = threadIdx.x;
    __shared__ float wbuf[L_];
    __shared__ float r1[4], r2[4];
    const float* s = SCp + (size_t)b * L_;

    float m = -1e30f;
    for (int j = t; j < L_; j += 256) m = fmaxf(m, s[j]);
#pragma unroll
    for (int o = 32; o > 0; o >>= 1) m = fmaxf(m, __shfl_xor(m, o));
    if ((t & 63) == 0) r1[t >> 6] = m;
    __syncthreads();
    m = fmaxf(fmaxf(r1[0], r1[1]), fmaxf(r1[2], r1[3]));

    float sum = 0.f;
    for (int j = t; j < L_; j += 256) {
        float e = expf(s[j] - m);
        wbuf[j] = e;
        sum += e;
    }
#pragma unroll
    for (int o = 32; o > 0; o >>= 1) sum += __shfl_xor(sum, o);
    if ((t & 63) == 0) r2[t >> 6] = sum;
    __syncthreads();
    sum = r2[0] + r2[1] + r2[2] + r2[3];
    float inv = 1.0f / sum;

    float acc = 0.f;
    const float* xb = X + (size_t)b * L_ * D_;
    for (int l = 0; l < L_; ++l) acc += wbuf[l] * xb[(size_t)l * D_ + t];
    outp[b * D_ + t] = acc * inv;
}

// ---------------------------------------------------------------------------
extern "C" void kernel_launch(void* const* d_in, const int* in_sizes, int n_in,
                              void* d_out, int out_size, void* d_ws, size_t ws_size,
                              hipStream_t stream)
{
    const float* gene   = (const float*)d_in[0];
    const float* coords = (const float*)d_in[1];
    const float* w_in   = (const float*)d_in[2];
    const float* b_in   = (const float*)d_in[3];
    const float* w_cls  = (const float*)d_in[4];
    const float* b_cls  = (const float*)d_in[5];
    const float* qkv_w  = (const float*)d_in[6];
    const float* qkv_b  = (const float*)d_in[7];
    const float* ln1_g  = (const float*)d_in[8];
    const float* ln1_b  = (const float*)d_in[9];
    const float* ffn_w1 = (const float*)d_in[10];
    const float* ffn_b1 = (const float*)d_in[11];
    const float* ffn_w2 = (const float*)d_in[12];
    const float* ffn_b2 = (const float*)d_in[13];
    const float* ln2_g  = (const float*)d_in[14];
    const float* ln2_b  = (const float*)d_in[15];
    const float* th1_w  = (const float*)d_in[16];
    const float* th1_b  = (const float*)d_in[17];
    const float* bn_g   = (const float*)d_in[18];
    const float* bn_b   = (const float*)d_in[19];
    const float* th2_w  = (const float*)d_in[20];
    const float* th2_b  = (const float*)d_in[21];
    float* out = (float*)d_out;

    const int ROWS = B_ * L_;   // 29248
    char* p = (char*)d_ws;
    float*  X    = (float*)p;  p += (size_t)MPAD * 256 * 4;
    float*  AO   = (float*)p;  p += (size_t)MPAD * 256 * 4;
    ushort* Xb   = (ushort*)p; p += (size_t)MPAD * 256 * 2;
    ushort* SH   = (ushort*)p; p += (size_t)MPAD * 1024 * 2;
    ushort* qkvT = (ushort*)p; p += (size_t)NL_ * 768 * 256 * 2;
    ushort* w1T  = (ushort*)p; p += (size_t)NL_ * 1024 * 256 * 2;
    ushort* w2T  = (ushort*)p; p += (size_t)NL_ * 256 * 1024 * 2;
    float*  SCp  = (float*)p;  p += (size_t)ROWS * 4;

    wcast_kernel<<<dim3(768 / 32, 256 / 32, NL_), dim3(32, 8), 0, stream>>>(qkv_w, qkvT, 256, 768);
    wcast_kernel<<<dim3(1024 / 32, 256 / 32, NL_), dim3(32, 8), 0, stream>>>(ffn_w1, w1T, 256, 1024);
    wcast_kernel<<<dim3(256 / 32, 1024 / 32, NL_), dim3(32, 8), 0, stream>>>(ffn_w2, w2T, 1024, 256);

    sgemm_kernel<<<dim3(D_ / 64, (B_ * NT_) / 64), 256, 0, stream>>>(
        gene, w_in, b_in, X, B_ * NT_, D_, TOK_);
    cls_kernel<<<B_, 256, 0, stream>>>(coords, w_cls, b_cls, X);
    castx_kernel<<<(MPAD * 256 / 4) / 256, 256, 0, stream>>>(X, Xb);

    for (int l = 0; l < NL_; ++l) {
        mfma_gemm<<<dim3(768 / 128, MPAD / 128), 256, 0, stream>>>(
            Xb, qkvT + (size_t)l * 768 * 256, qkv_b + l * 768, SH, 768, 256, 0, 1);
        attn_kernel<<<dim3(15, H_, B_), 256, 0, stream>>>(SH, AO);
        ln_kernel<<<ROWS, 256, 0, stream>>>(X, AO, ln1_g + l * D_, ln1_b + l * D_, X, Xb);
        mfma_gemm<<<dim3(1024 / 128, MPAD / 128), 256, 0, stream>>>(
            Xb, w1T + (size_t)l * 1024 * 256, ffn_b1 + l * 1024, SH, 1024, 256, 1, 1);
        mfma_gemm<<<dim3(256 / 128, MPAD / 128), 256, 0, stream>>>(
            SH, w2T + (size_t)l * 256 * 1024, ffn_b2 + l * D_, AO, 256, 1024, 0, 0);
        ln_kernel<<<ROWS, 256, 0, stream>>>(X, AO, ln2_g + l * D_, ln2_b + l * D_, X, Xb);
    }

    head1_kernel<<<ROWS / 8, 256, 0, stream>>>(
        X, th1_w, th1_b, bn_g, bn_b, th2_w, th2_b, SCp);
    head2_kernel<<<B_, 256, 0, stream>>>(SCp, X, out);
}

// Round 5
// 1242.943 us; speedup vs baseline: 6.4665x; 1.3283x over previous
//
#include <hip/hip_runtime.h>
#include <math.h>

#define B_   64
#define TOK_ 64
#define NT_  456
#define L_   457
#define D_   256
#define H_   8
#define HD_  32
#define FF_  1024
#define NL_  4
#define PH_  32
#define MPAD 29312   // 229 * 128 (rows padded for 128-row GEMM tiles)

typedef unsigned int uint;
typedef unsigned short ushort;
typedef __bf16 v8bf __attribute__((ext_vector_type(8)));
typedef float v4f __attribute__((ext_vector_type(4)));

__device__ __forceinline__ float bu2f(ushort x) {
    return __uint_as_float(((uint)x) << 16);
}
__device__ __forceinline__ ushort f2bu(float f) {
    union { float f; uint u; } x; x.f = f;
    uint r = (x.u + 0x7fffu + ((x.u >> 16) & 1u)) >> 16;
    return (ushort)r;
}

// async global->LDS 16B copy; lds base wave-uniform, data at base + lane*16.
__device__ __forceinline__ void gload16(const void* g, void* l) {
    __builtin_amdgcn_global_load_lds(
        (const __attribute__((address_space(1))) void*)(unsigned long long)(uintptr_t)g,
        (__attribute__((address_space(3))) void*)(uint)(uintptr_t)l,
        16, 0, 0);
}

// ---------------------------------------------------------------------------
// bf16 MFMA GEMM (m97 structure): C[M,N] = A[M,K]·W^T[N,K] + bias.
// ---------------------------------------------------------------------------
__global__ __launch_bounds__(256) void mfma_gemm(
    const ushort* __restrict__ A, const ushort* __restrict__ WT,
    const float* __restrict__ bias, void* __restrict__ Cout,
    int N, int K, int relu, int obf16)
{
    __shared__ ushort As[128 * 32];
    __shared__ ushort Bs[128 * 32];
    int tid = threadIdx.x;
    int wave = tid >> 6, lane = tid & 63;
    int colblk = blockIdx.x * 128;
    int rowblk = blockIdx.y * 128;
    int wm = wave >> 1, wn = wave & 1;

    v4f acc[4][4];
#pragma unroll
    for (int i = 0; i < 4; ++i)
#pragma unroll
        for (int j = 0; j < 4; ++j) acc[i][j] = (v4f)0.0f;

    int fr = lane & 15, fq = lane >> 4;
    int scol = fq ^ (lane & 3) ^ ((lane >> 2) & 1);

    int c0 = wave * 64 + lane;
    int r0 = c0 >> 2, k0g = (c0 & 3) ^ (r0 & 3) ^ ((r0 >> 2) & 1);
    int c1 = 256 + c0;
    int r1 = c1 >> 2, k1g = (c1 & 3) ^ (r1 & 3) ^ ((r1 >> 2) & 1);

    const ushort* Ag0 = A + (size_t)(rowblk + r0) * K + k0g * 8;
    const ushort* Ag1 = A + (size_t)(rowblk + r1) * K + k1g * 8;
    const ushort* Bg0 = WT + (size_t)(colblk + r0) * K + k0g * 8;
    const ushort* Bg1 = WT + (size_t)(colblk + r1) * K + k1g * 8;
    ushort* lA0 = As + (size_t)(wave * 64) * 8;
    ushort* lA1 = As + (size_t)(256 + wave * 64) * 8;
    ushort* lB0 = Bs + (size_t)(wave * 64) * 8;
    ushort* lB1 = Bs + (size_t)(256 + wave * 64) * 8;

    for (int kt = 0; kt < K; kt += 32) {
        gload16(Ag0 + kt, lA0);
        gload16(Ag1 + kt, lA1);
        gload16(Bg0 + kt, lB0);
        gload16(Bg1 + kt, lB1);
        __syncthreads();

        v8bf a[4], b[4];
#pragma unroll
        for (int mi = 0; mi < 4; ++mi)
            a[mi] = *(const v8bf*)(As + (size_t)(wm * 64 + mi * 16 + fr) * 32 + scol * 8);
#pragma unroll
        for (int ni = 0; ni < 4; ++ni)
            b[ni] = *(const v8bf*)(Bs + (size_t)(wn * 64 + ni * 16 + fr) * 32 + scol * 8);
#pragma unroll
        for (int mi = 0; mi < 4; ++mi)
#pragma unroll
            for (int ni = 0; ni < 4; ++ni)
                acc[mi][ni] = __builtin_amdgcn_mfma_f32_16x16x32_bf16(
                    a[mi], b[ni], acc[mi][ni], 0, 0, 0);
        __syncthreads();
    }

#pragma unroll
    for (int ni = 0; ni < 4; ++ni) {
        int col = colblk + wn * 64 + ni * 16 + fr;
        float bv = bias[col];
#pragma unroll
        for (int mi = 0; mi < 4; ++mi) {
            int row = rowblk + wm * 64 + mi * 16 + fq * 4;
#pragma unroll
            for (int r = 0; r < 4; ++r) {
                float v = acc[mi][ni][r] + bv;
                if (relu) v = fmaxf(v, 0.f);
                if (obf16)
                    ((ushort*)Cout)[(size_t)(row + r) * N + col] = f2bu(v);
                else
                    ((float*)Cout)[(size_t)(row + r) * N + col] = v;
            }
        }
    }
}

// ---------------------------------------------------------------------------
__global__ __launch_bounds__(256) void wcast_kernel(
    const float* __restrict__ W, ushort* __restrict__ WT, int K, int N)
{
    __shared__ float t[32][33];
    const float* Wl = W + (size_t)blockIdx.z * K * N;
    ushort* WTl = WT + (size_t)blockIdx.z * K * N;
    int n0 = blockIdx.x * 32, k0 = blockIdx.y * 32;
    int tx = threadIdx.x, ty = threadIdx.y;
#pragma unroll
    for (int r = 0; r < 32; r += 8)
        t[ty + r][tx] = Wl[(size_t)(k0 + ty + r) * N + n0 + tx];
    __syncthreads();
#pragma unroll
    for (int r = 0; r < 32; r += 8)
        WTl[(size_t)(n0 + ty + r) * K + k0 + tx] = f2bu(t[tx][ty + r]);
}

// ---------------------------------------------------------------------------
// fp32 SGEMM for the embed GEMM only; row-remap; writes fp32 X and bf16 Xb.
// ---------------------------------------------------------------------------
__global__ __launch_bounds__(256) void sgemm_kernel(
    const float* __restrict__ A, const float* __restrict__ W,
    const float* __restrict__ bias, float* __restrict__ C,
    ushort* __restrict__ Cb, int M, int N, int K)
{
    __shared__ float As_[16][64];
    __shared__ float Bs_[16][64];
    int tid = threadIdx.x;
    int rowblk = blockIdx.y * 64;
    int colblk = blockIdx.x * 64;
    int a_row = tid & 63, a_q = tid >> 6;
    int b_kr = tid >> 4, b_cg = tid & 15;
    int rm = tid >> 4, cn = tid & 15;
    float acc[4][4] = {};
    const float* Aptr = A + (size_t)(rowblk + a_row) * K;
    for (int kt = 0; kt < K; kt += 16) {
        float4 av = *(const float4*)(Aptr + kt + a_q * 4);
        float4 bv = *(const float4*)(W + (size_t)(kt + b_kr) * N + colblk + b_cg * 4);
        As_[a_q * 4 + 0][a_row] = av.x;
        As_[a_q * 4 + 1][a_row] = av.y;
        As_[a_q * 4 + 2][a_row] = av.z;
        As_[a_q * 4 + 3][a_row] = av.w;
        *(float4*)&Bs_[b_kr][b_cg * 4] = bv;
        __syncthreads();
#pragma unroll
        for (int kk = 0; kk < 16; ++kk) {
            float4 a4 = *(const float4*)&As_[kk][rm * 4];
            float4 b4 = *(const float4*)&Bs_[kk][cn * 4];
            float ar[4] = {a4.x, a4.y, a4.z, a4.w};
            float br[4] = {b4.x, b4.y, b4.z, b4.w};
#pragma unroll
            for (int i = 0; i < 4; ++i)
#pragma unroll
                for (int j = 0; j < 4; ++j) acc[i][j] += ar[i] * br[j];
        }
        __syncthreads();
    }
    float4 bv = *(const float4*)(bias + colblk + cn * 4);
    float bb[4] = {bv.x, bv.y, bv.z, bv.w};
#pragma unroll
    for (int i = 0; i < 4; ++i) {
        int grow = rowblk + rm * 4 + i;
        size_t orow = (size_t)(grow + grow / NT_ + 1);
        float4 r;
        r.x = acc[i][0] + bb[0]; r.y = acc[i][1] + bb[1];
        r.z = acc[i][2] + bb[2]; r.w = acc[i][3] + bb[3];
        *(float4*)(C + orow * N + colblk + cn * 4) = r;
        ushort4 h;
        h.x = f2bu(r.x); h.y = f2bu(r.y); h.z = f2bu(r.z); h.w = f2bu(r.w);
        *(ushort4*)(Cb + orow * N + colblk + cn * 4) = h;
    }
}

__global__ __launch_bounds__(256) void cls_kernel(
    const float* __restrict__ coords, const float* __restrict__ w_cls,
    const float* __restrict__ b_cls, float* __restrict__ X,
    ushort* __restrict__ Xb)
{
    int b = blockIdx.x;
    int t = threadIdx.x;
    float c0 = coords[b * 3 + 0], c1 = coords[b * 3 + 1], c2 = coords[b * 3 + 2];
    float v = c0 * w_cls[t] + c1 * w_cls[D_ + t] + c2 * w_cls[2 * D_ + t] + b_cls[t];
    X[(size_t)b * L_ * D_ + t] = v;
    Xb[(size_t)b * L_ * D_ + t] = f2bu(v);
}

// ---------------------------------------------------------------------------
// MFMA attention v2: one block per (b,h), 512 threads (8 waves).
// K and V^T staged ONCE into LDS; 8 q-tiles of 64 rows.
// Fused softmax: QK epilogue writes P = exp(s*scale - slope|i-j|) directly
// (shift-free softmax: |s*scale| <= ~1, bias <= 0 -> no overflow; sum >= e^-1.5)
// and accumulates row sums in registers (16-lane shuffles).
// ---------------------------------------------------------------------------
__global__ __launch_bounds__(512) void attn_kernel(
    const ushort* __restrict__ qkv, float* __restrict__ out)
{
    __shared__ ushort Qs[64][40];     //  5.0 KB
    __shared__ ushort Ks[464][40];    // 36.3 KB
    __shared__ ushort Vt[32][488];    // 30.5 KB (cols 457..487 zeroed)
    __shared__ ushort Sc[64][488];    // 61.0 KB (cols 464..479 zeroed)
    __shared__ float rs[4][2][16];

    int h = blockIdx.x, b = blockIdx.y;
    int tid = threadIdx.x;
    int wave = tid >> 6, lane = tid & 63;
    int fr = lane & 15, fq = lane >> 4;
    int wq = wave >> 1, wk = wave & 1;
    const float scale = 0.17677669529663687f;
    float slope = (h < 4) ? 1.0f : 0.5f;
    const ushort* base = qkv + (size_t)b * L_ * 768;

    // stage K rows 0..463 (zero-fill >= 457), pitch 40 ushorts
    for (int j = tid >> 2; j < 464; j += 128) {
        int c8 = (tid & 3) * 8;
        uint4 u = make_uint4(0u, 0u, 0u, 0u);
        if (j < L_) u = *(const uint4*)(base + (size_t)j * 768 + 256 + h * 32 + c8);
        *(uint4*)&Ks[j][c8] = u;
    }
    // stage V transposed; per-wave 64 consecutive j -> 2-way banks (free)
    for (int m = wave; m < 32; m += 8) {
        int dg = (m >> 3) * 8, jb = m & 7;
        int j = jb * 64 + lane;
        uint4 u = make_uint4(0u, 0u, 0u, 0u);
        if (j < L_) u = *(const uint4*)(base + (size_t)j * 768 + 512 + h * 32 + dg);
        if (j < 488) {
            const ushort* pu = (const ushort*)&u;
#pragma unroll
            for (int e = 0; e < 8; ++e) Vt[dg + e][j] = pu[e];
        }
    }
    __syncthreads();

    for (int qt = 0; qt < 8; ++qt) {
        int q0 = qt * 64;
        // stage Q tile (zero-fill beyond L)
        {
            int i = tid >> 3, c4 = (tid & 7) * 4;
            uint2 u = make_uint2(0u, 0u);
            if (q0 + i < L_) u = *(const uint2*)(base + (size_t)(q0 + i) * 768 + h * 32 + c4);
            *(uint2*)&Qs[i][c4] = u;
        }
        // zero Sc pad cols 464..479
        {
            int r = tid >> 3, c = (tid & 7) * 2;
            *(uint*)&Sc[r][464 + c] = 0u;
        }
        __syncthreads();

        v8bf qfrag = *(const v8bf*)&Qs[wq * 16 + fr][fq * 8];
        float ps[4] = {0.f, 0.f, 0.f, 0.f};
        int qbase = q0 + wq * 16 + fq * 4;

        for (int kt = wk; kt < 29; kt += 2) {
            v8bf kfrag = *(const v8bf*)&Ks[kt * 16 + fr][fq * 8];
            v4f d = (v4f)0.0f;
            d = __builtin_amdgcn_mfma_f32_16x16x32_bf16(qfrag, kfrag, d, 0, 0, 0);
            int col = kt * 16 + fr;
            float fcol = (float)col;
#pragma unroll
            for (int r = 0; r < 4; ++r) {
                float p = 0.f;
                if (col < L_)
                    p = __expf(d[r] * scale - slope * fabsf((float)(qbase + r) - fcol));
                ushort pb = f2bu(p);
                Sc[wq * 16 + fq * 4 + r][col] = pb;
                ps[r] += bu2f(pb);
            }
        }
        // reduce row sums over the 16 fr lanes, publish per (wq,wk)
#pragma unroll
        for (int r = 0; r < 4; ++r) {
#pragma unroll
            for (int o = 1; o < 16; o <<= 1) ps[r] += __shfl_xor(ps[r], o);
        }
        if (fr == 0) {
#pragma unroll
            for (int r = 0; r < 4; ++r) rs[wq][wk][fq * 4 + r] = ps[r];
        }
        __syncthreads();

        float rsum[4];
#pragma unroll
        for (int r = 0; r < 4; ++r)
            rsum[r] = rs[wq][0][fq * 4 + r] + rs[wq][1][fq * 4 + r];

        // P @ V : wave (wq,wk) computes O tile rows wq*16.., cols wk*16..
        v4f oacc = (v4f)0.0f;
#pragma unroll
        for (int kc = 0; kc < 15; ++kc) {
            v8bf pfrag = *(const v8bf*)&Sc[wq * 16 + fr][kc * 32 + fq * 8];
            v8bf vfrag = *(const v8bf*)&Vt[wk * 16 + fr][kc * 32 + fq * 8];
            oacc = __builtin_amdgcn_mfma_f32_16x16x32_bf16(pfrag, vfrag, oacc, 0, 0, 0);
        }
#pragma unroll
        for (int r = 0; r < 4; ++r) {
            int row = qbase + r;
            if (row < L_)
                out[(size_t)(b * L_ + row) * D_ + h * 32 + wk * 16 + fr] = oacc[r] / rsum[r];
        }
        __syncthreads();
    }
}

// ---------------------------------------------------------------------------
// Fused residual+LN: wave per row, shuffle-only, 4 rows/block.
// ---------------------------------------------------------------------------
__global__ __launch_bounds__(256) void ln_kernel(
    const float* __restrict__ res, const float* __restrict__ y,
    const float* __restrict__ g, const float* __restrict__ bb,
    float* __restrict__ xout, ushort* __restrict__ xbout)
{
    int row = blockIdx.x * 4 + (threadIdx.x >> 6);
    int lane = threadIdx.x & 63;
    size_t off = (size_t)row * D_ + lane * 4;
    float4 rv = *(const float4*)(res + off);
    float4 yv = *(const float4*)(y + off);
    float4 v;
    v.x = rv.x + yv.x; v.y = rv.y + yv.y; v.z = rv.z + yv.z; v.w = rv.w + yv.w;

    float s = v.x + v.y + v.z + v.w;
#pragma unroll
    for (int o = 1; o < 64; o <<= 1) s += __shfl_xor(s, o);
    float mean = s * (1.0f / 256.0f);

    float4 d;
    d.x = v.x - mean; d.y = v.y - mean; d.z = v.z - mean; d.w = v.w - mean;
    float sq = d.x * d.x + d.y * d.y + d.z * d.z + d.w * d.w;
#pragma unroll
    for (int o = 1; o < 64; o <<= 1) sq += __shfl_xor(sq, o);
    float rstd = rsqrtf(sq * (1.0f / 256.0f) + 1e-5f);

    float4 gv = *(const float4*)(g + lane * 4);
    float4 bv = *(const float4*)(bb + lane * 4);
    float4 o;
    o.x = d.x * rstd * gv.x + bv.x;
    o.y = d.y * rstd * gv.y + bv.y;
    o.z = d.z * rstd * gv.z + bv.z;
    o.w = d.w * rstd * gv.w + bv.w;
    *(float4*)(xout + off) = o;
    ushort4 hb;
    hb.x = f2bu(o.x); hb.y = f2bu(o.y); hb.z = f2bu(o.z); hb.w = f2bu(o.w);
    *(ushort4*)(xbout + off) = hb;
}

__global__ __launch_bounds__(256) void head1_kernel(
    const float* __restrict__ X, const float* __restrict__ w1,
    const float* __restrict__ b1, const float* __restrict__ bng,
    const float* __restrict__ bnb, const float* __restrict__ w2,
    const float* __restrict__ b2, float* __restrict__ SCp)
{
    int row = blockIdx.x * 8 + (threadIdx.x >> 5);
    int j = threadIdx.x & 31;
    const float* x = X + (size_t)row * D_;
    float acc = 0.f;
    for (int d = 0; d < D_; ++d) acc += x[d] * w1[d * PH_ + j];
    acc += b1[j];
    float hb = acc * (bng[j] * rsqrtf(1.0f + 1e-5f)) + bnb[j];
    const float c = 0.7978845608028654f;
    float t = tanhf(c * (hb + 0.044715f * hb * hb * hb));
    float gl = 0.5f * hb * (1.0f + t);
    float sp = gl * w2[j];
#pragma unroll
    for (int o = 16; o > 0; o >>= 1) sp += __shfl_xor(sp, o);
    if (j == 0) SCp[row] = sp + b2[0];
}

// ---------------------------------------------------------------------------
// head2: block (colgroup, b); 64 cols x 4 L-partitions per block.
// ---------------------------------------------------------------------------
__global__ __launch_bounds__(256) void head2_kernel(
    const float* __restrict__ SCp, const float* __restrict__ X,
    float* __restrict__ outp)
{
    int cg = blockIdx.x, b = blockIdx.y;
    int tid = threadIdx.x;
    __shared__ float wbuf[L_];
    __shared__ float r1[4], r2[4];
    __shared__ float part[4][64];
    const float* s = SCp + (size_t)b * L_;

    float m = -1e30f;
    for (int j = tid; j < L_; j += 256) m = fmaxf(m, s[j]);
#pragma unroll
    for (int o = 1; o < 64; o <<= 1) m = fmaxf(m, __shfl_xor(m, o));
    if ((tid & 63) == 0) r1[tid >> 6] = m;
    __syncthreads();
    m = fmaxf(fmaxf(r1[0], r1[1]), fmaxf(r1[2], r1[3]));

    float sum = 0.f;
    for (int j = tid; j < L_; j += 256) {
        float e = __expf(s[j] - m);
        wbuf[j] = e;
        sum += e;
    }
#pragma unroll
    for (int o = 1; o < 64; o <<= 1) sum += __shfl_xor(sum, o);
    if ((tid & 63) == 0) r2[tid >> 6] = sum;
    __syncthreads();
    float inv = 1.0f / (r2[0] + r2[1] + r2[2] + r2[3]);

    int c = tid & 63, pt = tid >> 6;
    int col = cg * 64 + c;
    float acc = 0.f;
    const float* xb = X + (size_t)b * L_ * D_ + col;
    for (int l = pt; l < L_; l += 4) acc += wbuf[l] * xb[(size_t)l * D_];
    part[pt][c] = acc;
    __syncthreads();
    if (pt == 0)
        outp[b * D_ + col] = (part[0][c] + part[1][c] + part[2][c] + part[3][c]) * inv;
}

// ---------------------------------------------------------------------------
extern "C" void kernel_launch(void* const* d_in, const int* in_sizes, int n_in,
                              void* d_out, int out_size, void* d_ws, size_t ws_size,
                              hipStream_t stream)
{
    const float* gene   = (const float*)d_in[0];
    const float* coords = (const float*)d_in[1];
    const float* w_in   = (const float*)d_in[2];
    const float* b_in   = (const float*)d_in[3];
    const float* w_cls  = (const float*)d_in[4];
    const float* b_cls  = (const float*)d_in[5];
    const float* qkv_w  = (const float*)d_in[6];
    const float* qkv_b  = (const float*)d_in[7];
    const float* ln1_g  = (const float*)d_in[8];
    const float* ln1_b  = (const float*)d_in[9];
    const float* ffn_w1 = (const float*)d_in[10];
    const float* ffn_b1 = (const float*)d_in[11];
    const float* ffn_w2 = (const float*)d_in[12];
    const float* ffn_b2 = (const float*)d_in[13];
    const float* ln2_g  = (const float*)d_in[14];
    const float* ln2_b  = (const float*)d_in[15];
    const float* th1_w  = (const float*)d_in[16];
    const float* th1_b  = (const float*)d_in[17];
    const float* bn_g   = (const float*)d_in[18];
    const float* bn_b   = (const float*)d_in[19];
    const float* th2_w  = (const float*)d_in[20];
    const float* th2_b  = (const float*)d_in[21];
    float* out = (float*)d_out;

    const int ROWS = B_ * L_;   // 29248
    char* p = (char*)d_ws;
    float*  X    = (float*)p;  p += (size_t)MPAD * 256 * 4;
    float*  AO   = (float*)p;  p += (size_t)MPAD * 256 * 4;
    ushort* Xb   = (ushort*)p; p += (size_t)MPAD * 256 * 2;
    ushort* SH   = (ushort*)p; p += (size_t)MPAD * 1024 * 2;
    ushort* qkvT = (ushort*)p; p += (size_t)NL_ * 768 * 256 * 2;
    ushort* w1T  = (ushort*)p; p += (size_t)NL_ * 1024 * 256 * 2;
    ushort* w2T  = (ushort*)p; p += (size_t)NL_ * 256 * 1024 * 2;
    float*  SCp  = (float*)p;  p += (size_t)ROWS * 4;

    wcast_kernel<<<dim3(768 / 32, 256 / 32, NL_), dim3(32, 8), 0, stream>>>(qkv_w, qkvT, 256, 768);
    wcast_kernel<<<dim3(1024 / 32, 256 / 32, NL_), dim3(32, 8), 0, stream>>>(ffn_w1, w1T, 256, 1024);
    wcast_kernel<<<dim3(256 / 32, 1024 / 32, NL_), dim3(32, 8), 0, stream>>>(ffn_w2, w2T, 1024, 256);

    sgemm_kernel<<<dim3(D_ / 64, (B_ * NT_) / 64), 256, 0, stream>>>(
        gene, w_in, b_in, X, Xb, B_ * NT_, D_, TOK_);
    cls_kernel<<<B_, 256, 0, stream>>>(coords, w_cls, b_cls, X, Xb);

    for (int l = 0; l < NL_; ++l) {
        mfma_gemm<<<dim3(768 / 128, MPAD / 128), 256, 0, stream>>>(
            Xb, qkvT + (size_t)l * 768 * 256, qkv_b + l * 768, SH, 768, 256, 0, 1);
        attn_kernel<<<dim3(H_, B_), 512, 0, stream>>>(SH, AO);
        ln_kernel<<<ROWS / 4, 256, 0, stream>>>(X, AO, ln1_g + l * D_, ln1_b + l * D_, X, Xb);
        mfma_gemm<<<dim3(1024 / 128, MPAD / 128), 256, 0, stream>>>(
            Xb, w1T + (size_t)l * 1024 * 256, ffn_b1 + l * 1024, SH, 1024, 256, 1, 1);
        mfma_gemm<<<dim3(256 / 128, MPAD / 128), 256, 0, stream>>>(
            SH, w2T + (size_t)l * 256 * 1024, ffn_b2 + l * D_, AO, 256, 1024, 0, 0);
        ln_kernel<<<ROWS / 4, 256, 0, stream>>>(X, AO, ln2_g + l * D_, ln2_b + l * D_, X, Xb);
    }

    head1_kernel<<<ROWS / 8, 256, 0, stream>>>(
        X, th1_w, th1_b, bn_g, bn_b, th2_w, th2_b, SCp);
    head2_kernel<<<dim3(4, B_), 256, 0, stream>>>(SCp, X, out);
}

// Round 6
// 1215.011 us; speedup vs baseline: 6.6152x; 1.0230x over previous
//
#include <hip/hip_runtime.h>
#include <math.h>

#define B_   64
#define TOK_ 64
#define NT_  456
#define L_   457
#define D_   256
#define H_   8
#define HD_  32
#define FF_  1024
#define NL_  4
#define PH_  32
#define MPAD 29312   // 229 * 128 (rows padded for 128-row GEMM tiles)

typedef unsigned int uint;
typedef unsigned short ushort;
typedef __bf16 v8bf __attribute__((ext_vector_type(8)));
typedef float v4f __attribute__((ext_vector_type(4)));

__device__ __forceinline__ float bu2f(ushort x) {
    return __uint_as_float(((uint)x) << 16);
}
__device__ __forceinline__ ushort f2bu(float f) {
    union { float f; uint u; } x; x.f = f;
    uint r = (x.u + 0x7fffu + ((x.u >> 16) & 1u)) >> 16;
    return (ushort)r;
}
// pack two floats to packed bf16 (RNE); hw instr if available
__device__ __forceinline__ uint pack_bf2(float a, float b) {
#if __has_builtin(__builtin_amdgcn_cvt_pk_bf16_f32)
    typedef __bf16 bf2v __attribute__((ext_vector_type(2)));
    bf2v v = __builtin_amdgcn_cvt_pk_bf16_f32(a, b);
    return *(uint*)&v;
#else
    return (uint)f2bu(a) | ((uint)f2bu(b) << 16);
#endif
}

// async global->LDS 16B copy; lds base wave-uniform, data at base + lane*16.
__device__ __forceinline__ void gload16(const void* g, void* l) {
    __builtin_amdgcn_global_load_lds(
        (const __attribute__((address_space(1))) void*)(unsigned long long)(uintptr_t)g,
        (__attribute__((address_space(3))) void*)(uint)(uintptr_t)l,
        16, 0, 0);
}

// ---------------------------------------------------------------------------
// bf16 MFMA GEMM (m97 structure): C[M,N] = A[M,K]·W^T[N,K] + bias.
// ---------------------------------------------------------------------------
__global__ __launch_bounds__(256) void mfma_gemm(
    const ushort* __restrict__ A, const ushort* __restrict__ WT,
    const float* __restrict__ bias, void* __restrict__ Cout,
    int N, int K, int relu, int obf16)
{
    __shared__ ushort As[128 * 32];
    __shared__ ushort Bs[128 * 32];
    int tid = threadIdx.x;
    int wave = tid >> 6, lane = tid & 63;
    int colblk = blockIdx.x * 128;
    int rowblk = blockIdx.y * 128;
    int wm = wave >> 1, wn = wave & 1;

    v4f acc[4][4];
#pragma unroll
    for (int i = 0; i < 4; ++i)
#pragma unroll
        for (int j = 0; j < 4; ++j) acc[i][j] = (v4f)0.0f;

    int fr = lane & 15, fq = lane >> 4;
    int scol = fq ^ (lane & 3) ^ ((lane >> 2) & 1);

    int c0 = wave * 64 + lane;
    int r0 = c0 >> 2, k0g = (c0 & 3) ^ (r0 & 3) ^ ((r0 >> 2) & 1);
    int c1 = 256 + c0;
    int r1 = c1 >> 2, k1g = (c1 & 3) ^ (r1 & 3) ^ ((r1 >> 2) & 1);

    const ushort* Ag0 = A + (size_t)(rowblk + r0) * K + k0g * 8;
    const ushort* Ag1 = A + (size_t)(rowblk + r1) * K + k1g * 8;
    const ushort* Bg0 = WT + (size_t)(colblk + r0) * K + k0g * 8;
    const ushort* Bg1 = WT + (size_t)(colblk + r1) * K + k1g * 8;
    ushort* lA0 = As + (size_t)(wave * 64) * 8;
    ushort* lA1 = As + (size_t)(256 + wave * 64) * 8;
    ushort* lB0 = Bs + (size_t)(wave * 64) * 8;
    ushort* lB1 = Bs + (size_t)(256 + wave * 64) * 8;

    for (int kt = 0; kt < K; kt += 32) {
        gload16(Ag0 + kt, lA0);
        gload16(Ag1 + kt, lA1);
        gload16(Bg0 + kt, lB0);
        gload16(Bg1 + kt, lB1);
        __syncthreads();

        v8bf a[4], b[4];
#pragma unroll
        for (int mi = 0; mi < 4; ++mi)
            a[mi] = *(const v8bf*)(As + (size_t)(wm * 64 + mi * 16 + fr) * 32 + scol * 8);
#pragma unroll
        for (int ni = 0; ni < 4; ++ni)
            b[ni] = *(const v8bf*)(Bs + (size_t)(wn * 64 + ni * 16 + fr) * 32 + scol * 8);
#pragma unroll
        for (int mi = 0; mi < 4; ++mi)
#pragma unroll
            for (int ni = 0; ni < 4; ++ni)
                acc[mi][ni] = __builtin_amdgcn_mfma_f32_16x16x32_bf16(
                    a[mi], b[ni], acc[mi][ni], 0, 0, 0);
        __syncthreads();
    }

#pragma unroll
    for (int ni = 0; ni < 4; ++ni) {
        int col = colblk + wn * 64 + ni * 16 + fr;
        float bv = bias[col];
#pragma unroll
        for (int mi = 0; mi < 4; ++mi) {
            int row = rowblk + wm * 64 + mi * 16 + fq * 4;
#pragma unroll
            for (int r = 0; r < 4; ++r) {
                float v = acc[mi][ni][r] + bv;
                if (relu) v = fmaxf(v, 0.f);
                if (obf16)
                    ((ushort*)Cout)[(size_t)(row + r) * N + col] = f2bu(v);
                else
                    ((float*)Cout)[(size_t)(row + r) * N + col] = v;
            }
        }
    }
}

// ---------------------------------------------------------------------------
__global__ __launch_bounds__(256) void wcast_kernel(
    const float* __restrict__ W, ushort* __restrict__ WT, int K, int N)
{
    __shared__ float t[32][33];
    const float* Wl = W + (size_t)blockIdx.z * K * N;
    ushort* WTl = WT + (size_t)blockIdx.z * K * N;
    int n0 = blockIdx.x * 32, k0 = blockIdx.y * 32;
    int tx = threadIdx.x, ty = threadIdx.y;
#pragma unroll
    for (int r = 0; r < 32; r += 8)
        t[ty + r][tx] = Wl[(size_t)(k0 + ty + r) * N + n0 + tx];
    __syncthreads();
#pragma unroll
    for (int r = 0; r < 32; r += 8)
        WTl[(size_t)(n0 + ty + r) * K + k0 + tx] = f2bu(t[tx][ty + r]);
}

// ---------------------------------------------------------------------------
// fp32 SGEMM for the embed GEMM only; row-remap; writes fp32 X and bf16 Xb.
// ---------------------------------------------------------------------------
__global__ __launch_bounds__(256) void sgemm_kernel(
    const float* __restrict__ A, const float* __restrict__ W,
    const float* __restrict__ bias, float* __restrict__ C,
    ushort* __restrict__ Cb, int M, int N, int K)
{
    __shared__ float As_[16][64];
    __shared__ float Bs_[16][64];
    int tid = threadIdx.x;
    int rowblk = blockIdx.y * 64;
    int colblk = blockIdx.x * 64;
    int a_row = tid & 63, a_q = tid >> 6;
    int b_kr = tid >> 4, b_cg = tid & 15;
    int rm = tid >> 4, cn = tid & 15;
    float acc[4][4] = {};
    const float* Aptr = A + (size_t)(rowblk + a_row) * K;
    for (int kt = 0; kt < K; kt += 16) {
        float4 av = *(const float4*)(Aptr + kt + a_q * 4);
        float4 bv = *(const float4*)(W + (size_t)(kt + b_kr) * N + colblk + b_cg * 4);
        As_[a_q * 4 + 0][a_row] = av.x;
        As_[a_q * 4 + 1][a_row] = av.y;
        As_[a_q * 4 + 2][a_row] = av.z;
        As_[a_q * 4 + 3][a_row] = av.w;
        *(float4*)&Bs_[b_kr][b_cg * 4] = bv;
        __syncthreads();
#pragma unroll
        for (int kk = 0; kk < 16; ++kk) {
            float4 a4 = *(const float4*)&As_[kk][rm * 4];
            float4 b4 = *(const float4*)&Bs_[kk][cn * 4];
            float ar[4] = {a4.x, a4.y, a4.z, a4.w};
            float br[4] = {b4.x, b4.y, b4.z, b4.w};
#pragma unroll
            for (int i = 0; i < 4; ++i)
#pragma unroll
                for (int j = 0; j < 4; ++j) acc[i][j] += ar[i] * br[j];
        }
        __syncthreads();
    }
    float4 bv = *(const float4*)(bias + colblk + cn * 4);
    float bb[4] = {bv.x, bv.y, bv.z, bv.w};
#pragma unroll
    for (int i = 0; i < 4; ++i) {
        int grow = rowblk + rm * 4 + i;
        size_t orow = (size_t)(grow + grow / NT_ + 1);
        float4 r;
        r.x = acc[i][0] + bb[0]; r.y = acc[i][1] + bb[1];
        r.z = acc[i][2] + bb[2]; r.w = acc[i][3] + bb[3];
        *(float4*)(C + orow * N + colblk + cn * 4) = r;
        ushort4 h;
        h.x = f2bu(r.x); h.y = f2bu(r.y); h.z = f2bu(r.z); h.w = f2bu(r.w);
        *(ushort4*)(Cb + orow * N + colblk + cn * 4) = h;
    }
}

__global__ __launch_bounds__(256) void cls_kernel(
    const float* __restrict__ coords, const float* __restrict__ w_cls,
    const float* __restrict__ b_cls, float* __restrict__ X,
    ushort* __restrict__ Xb)
{
    int b = blockIdx.x;
    int t = threadIdx.x;
    float c0 = coords[b * 3 + 0], c1 = coords[b * 3 + 1], c2 = coords[b * 3 + 2];
    float v = c0 * w_cls[t] + c1 * w_cls[D_ + t] + c2 * w_cls[2 * D_ + t] + b_cls[t];
    X[(size_t)b * L_ * D_ + t] = v;
    Xb[(size_t)b * L_ * D_ + t] = f2bu(v);
}

// ---------------------------------------------------------------------------
// MFMA attention v3: one block per (b,h), 512 threads (8 waves).
// K/V^T staged once. QK uses SWAPPED operands (A=K, B=Q) so each lane's
// 4 score values are consecutive in k for a single q -> packed bf16
// ds_write_b64 (1 store per 4 elems) and register row-sums (2 shuffles/qt).
// Sc layout [q][k], pitch 496 ushorts (992B: 16B-aligned rows, 30-bank row
// step -> 16 distinct row offsets, conflict-free b128 reads).
// ---------------------------------------------------------------------------
__global__ __launch_bounds__(512) void attn_kernel(
    const ushort* __restrict__ qkv, float* __restrict__ out)
{
    __shared__ ushort Qs[64][40];     //  5.0 KB
    __shared__ ushort Ks[464][40];    // 36.3 KB
    __shared__ ushort Vt[32][488];    // 30.5 KB
    __shared__ ushort Sc[64][496];    // 62.0 KB  [q][k]
    __shared__ float rs[4][2][16];

    int h = blockIdx.x, b = blockIdx.y;
    int tid = threadIdx.x;
    int wave = tid >> 6, lane = tid & 63;
    int fr = lane & 15, fq = lane >> 4;
    int wq = wave >> 1, wk = wave & 1;
    const float scale = 0.17677669529663687f;
    float slope = (h < 4) ? 1.0f : 0.5f;
    const ushort* base = qkv + (size_t)b * L_ * 768;

    // stage K rows 0..463 (zero-fill >= 457), pitch 40 ushorts
    for (int j = tid >> 2; j < 464; j += 128) {
        int c8 = (tid & 3) * 8;
        uint4 u = make_uint4(0u, 0u, 0u, 0u);
        if (j < L_) u = *(const uint4*)(base + (size_t)j * 768 + 256 + h * 32 + c8);
        *(uint4*)&Ks[j][c8] = u;
    }
    // stage V transposed; per-wave 64 consecutive j -> 2-way banks (free)
    for (int m = wave; m < 32; m += 8) {
        int dg = (m >> 3) * 8, jb = m & 7;
        int j = jb * 64 + lane;
        uint4 u = make_uint4(0u, 0u, 0u, 0u);
        if (j < L_) u = *(const uint4*)(base + (size_t)j * 768 + 512 + h * 32 + dg);
        if (j < 488) {
            const ushort* pu = (const ushort*)&u;
#pragma unroll
            for (int e = 0; e < 8; ++e) Vt[dg + e][j] = pu[e];
        }
    }
    __syncthreads();

    for (int qt = 0; qt < 8; ++qt) {
        int q0 = qt * 64;
        // stage Q tile (zero-fill beyond L)
        {
            int i = tid >> 3, c4 = (tid & 7) * 4;
            uint2 u = make_uint2(0u, 0u);
            if (q0 + i < L_) u = *(const uint2*)(base + (size_t)(q0 + i) * 768 + h * 32 + c4);
            *(uint2*)&Qs[i][c4] = u;
        }
        // zero Sc pad cols 464..479 (read by PV chunk 14)
        {
            int r = tid >> 3, c = (tid & 7) * 2;
            *(uint*)&Sc[r][464 + c] = 0u;
        }
        __syncthreads();

        v8bf qfrag = *(const v8bf*)&Qs[wq * 16 + fr][fq * 8];
        float fmyq = (float)(q0 + wq * 16 + fr);   // this lane's q row
        float psum = 0.f;

        // QK: A=K, B=Q  ->  D: col(fr)=q, rows(fq*4+r)=k (consecutive)
        for (int kt = wk; kt < 29; kt += 2) {
            v8bf kfrag = *(const v8bf*)&Ks[kt * 16 + fr][fq * 8];
            v4f d = (v4f)0.0f;
            d = __builtin_amdgcn_mfma_f32_16x16x32_bf16(kfrag, qfrag, d, 0, 0, 0);
            float k0f = (float)(kt * 16 + fq * 4);
            float p[4];
#pragma unroll
            for (int r = 0; r < 4; ++r)
                p[r] = __expf(d[r] * scale - slope * fabsf(fmyq - (k0f + (float)r)));
            if (kt == 28) {   // wave-uniform tail mask (k 448..463 vs L=457)
#pragma unroll
                for (int r = 0; r < 4; ++r)
                    if (kt * 16 + fq * 4 + r >= L_) p[r] = 0.f;
            }
            uint2 w;
            w.x = pack_bf2(p[0], p[1]);
            w.y = pack_bf2(p[2], p[3]);
            *(uint2*)&Sc[wq * 16 + fr][kt * 16 + fq * 4] = w;
            psum += (p[0] + p[1]) + (p[2] + p[3]);
        }
        // row sum: reduce across fq (lanes fr, fr+16, fr+32, fr+48)
        psum += __shfl_xor(psum, 16);
        psum += __shfl_xor(psum, 32);
        if (fq == 0) rs[wq][wk][fr] = psum;
        __syncthreads();

        float rsum[4];
#pragma unroll
        for (int r = 0; r < 4; ++r)
            rsum[r] = rs[wq][0][fq * 4 + r] + rs[wq][1][fq * 4 + r];

        // P @ V : wave (wq,wk) -> O rows wq*16.., cols wk*16..
        v4f oacc = (v4f)0.0f;
#pragma unroll
        for (int kc = 0; kc < 15; ++kc) {
            v8bf pfrag = *(const v8bf*)&Sc[wq * 16 + fr][kc * 32 + fq * 8];
            v8bf vfrag = *(const v8bf*)&Vt[wk * 16 + fr][kc * 32 + fq * 8];
            oacc = __builtin_amdgcn_mfma_f32_16x16x32_bf16(pfrag, vfrag, oacc, 0, 0, 0);
        }
#pragma unroll
        for (int r = 0; r < 4; ++r) {
            int row = q0 + wq * 16 + fq * 4 + r;
            if (row < L_)
                out[(size_t)(b * L_ + row) * D_ + h * 32 + wk * 16 + fr] = oacc[r] / rsum[r];
        }
        __syncthreads();
    }
}

// ---------------------------------------------------------------------------
// Fused residual+LN: wave per row, shuffle-only, 4 rows/block.
// ---------------------------------------------------------------------------
__global__ __launch_bounds__(256) void ln_kernel(
    const float* __restrict__ res, const float* __restrict__ y,
    const float* __restrict__ g, const float* __restrict__ bb,
    float* __restrict__ xout, ushort* __restrict__ xbout)
{
    int row = blockIdx.x * 4 + (threadIdx.x >> 6);
    int lane = threadIdx.x & 63;
    size_t off = (size_t)row * D_ + lane * 4;
    float4 rv = *(const float4*)(res + off);
    float4 yv = *(const float4*)(y + off);
    float4 v;
    v.x = rv.x + yv.x; v.y = rv.y + yv.y; v.z = rv.z + yv.z; v.w = rv.w + yv.w;

    float s = v.x + v.y + v.z + v.w;
#pragma unroll
    for (int o = 1; o < 64; o <<= 1) s += __shfl_xor(s, o);
    float mean = s * (1.0f / 256.0f);

    float4 d;
    d.x = v.x - mean; d.y = v.y - mean; d.z = v.z - mean; d.w = v.w - mean;
    float sq = d.x * d.x + d.y * d.y + d.z * d.z + d.w * d.w;
#pragma unroll
    for (int o = 1; o < 64; o <<= 1) sq += __shfl_xor(sq, o);
    float rstd = rsqrtf(sq * (1.0f / 256.0f) + 1e-5f);

    float4 gv = *(const float4*)(g + lane * 4);
    float4 bv = *(const float4*)(bb + lane * 4);
    float4 o;
    o.x = d.x * rstd * gv.x + bv.x;
    o.y = d.y * rstd * gv.y + bv.y;
    o.z = d.z * rstd * gv.z + bv.z;
    o.w = d.w * rstd * gv.w + bv.w;
    *(float4*)(xout + off) = o;
    ushort4 hb;
    hb.x = f2bu(o.x); hb.y = f2bu(o.y); hb.z = f2bu(o.z); hb.w = f2bu(o.w);
    *(ushort4*)(xbout + off) = hb;
}

__global__ __launch_bounds__(256) void head1_kernel(
    const float* __restrict__ X, const float* __restrict__ w1,
    const float* __restrict__ b1, const float* __restrict__ bng,
    const float* __restrict__ bnb, const float* __restrict__ w2,
    const float* __restrict__ b2, float* __restrict__ SCp)
{
    int row = blockIdx.x * 8 + (threadIdx.x >> 5);
    int j = threadIdx.x & 31;
    const float* x = X + (size_t)row * D_;
    float acc = 0.f;
    for (int d = 0; d < D_; ++d) acc += x[d] * w1[d * PH_ + j];
    acc += b1[j];
    float hb = acc * (bng[j] * rsqrtf(1.0f + 1e-5f)) + bnb[j];
    const float c = 0.7978845608028654f;
    float t = tanhf(c * (hb + 0.044715f * hb * hb * hb));
    float gl = 0.5f * hb * (1.0f + t);
    float sp = gl * w2[j];
#pragma unroll
    for (int o = 16; o > 0; o >>= 1) sp += __shfl_xor(sp, o);
    if (j == 0) SCp[row] = sp + b2[0];
}

// ---------------------------------------------------------------------------
// head2: block (colgroup, b); 64 cols x 4 L-partitions per block.
// ---------------------------------------------------------------------------
__global__ __launch_bounds__(256) void head2_kernel(
    const float* __restrict__ SCp, const float* __restrict__ X,
    float* __restrict__ outp)
{
    int cg = blockIdx.x, b = blockIdx.y;
    int tid = threadIdx.x;
    __shared__ float wbuf[L_];
    __shared__ float r1[4], r2[4];
    __shared__ float part[4][64];
    const float* s = SCp + (size_t)b * L_;

    float m = -1e30f;
    for (int j = tid; j < L_; j += 256) m = fmaxf(m, s[j]);
#pragma unroll
    for (int o = 1; o < 64; o <<= 1) m = fmaxf(m, __shfl_xor(m, o));
    if ((tid & 63) == 0) r1[tid >> 6] = m;
    __syncthreads();
    m = fmaxf(fmaxf(r1[0], r1[1]), fmaxf(r1[2], r1[3]));

    float sum = 0.f;
    for (int j = tid; j < L_; j += 256) {
        float e = __expf(s[j] - m);
        wbuf[j] = e;
        sum += e;
    }
#pragma unroll
    for (int o = 1; o < 64; o <<= 1) sum += __shfl_xor(sum, o);
    if ((tid & 63) == 0) r2[tid >> 6] = sum;
    __syncthreads();
    float inv = 1.0f / (r2[0] + r2[1] + r2[2] + r2[3]);

    int c = tid & 63, pt = tid >> 6;
    int col = cg * 64 + c;
    float acc = 0.f;
    const float* xb = X + (size_t)b * L_ * D_ + col;
    for (int l = pt; l < L_; l += 4) acc += wbuf[l] * xb[(size_t)l * D_];
    part[pt][c] = acc;
    __syncthreads();
    if (pt == 0)
        outp[b * D_ + col] = (part[0][c] + part[1][c] + part[2][c] + part[3][c]) * inv;
}

// ---------------------------------------------------------------------------
extern "C" void kernel_launch(void* const* d_in, const int* in_sizes, int n_in,
                              void* d_out, int out_size, void* d_ws, size_t ws_size,
                              hipStream_t stream)
{
    const float* gene   = (const float*)d_in[0];
    const float* coords = (const float*)d_in[1];
    const float* w_in   = (const float*)d_in[2];
    const float* b_in   = (const float*)d_in[3];
    const float* w_cls  = (const float*)d_in[4];
    const float* b_cls  = (const float*)d_in[5];
    const float* qkv_w  = (const float*)d_in[6];
    const float* qkv_b  = (const float*)d_in[7];
    const float* ln1_g  = (const float*)d_in[8];
    const float* ln1_b  = (const float*)d_in[9];
    const float* ffn_w1 = (const float*)d_in[10];
    const float* ffn_b1 = (const float*)d_in[11];
    const float* ffn_w2 = (const float*)d_in[12];
    const float* ffn_b2 = (const float*)d_in[13];
    const float* ln2_g  = (const float*)d_in[14];
    const float* ln2_b  = (const float*)d_in[15];
    const float* th1_w  = (const float*)d_in[16];
    const float* th1_b  = (const float*)d_in[17];
    const float* bn_g   = (const float*)d_in[18];
    const float* bn_b   = (const float*)d_in[19];
    const float* th2_w  = (const float*)d_in[20];
    const float* th2_b  = (const float*)d_in[21];
    float* out = (float*)d_out;

    const int ROWS = B_ * L_;   // 29248
    char* p = (char*)d_ws;
    float*  X    = (float*)p;  p += (size_t)MPAD * 256 * 4;
    float*  AO   = (float*)p;  p += (size_t)MPAD * 256 * 4;
    ushort* Xb   = (ushort*)p; p += (size_t)MPAD * 256 * 2;
    ushort* SH   = (ushort*)p; p += (size_t)MPAD * 1024 * 2;
    ushort* qkvT = (ushort*)p; p += (size_t)NL_ * 768 * 256 * 2;
    ushort* w1T  = (ushort*)p; p += (size_t)NL_ * 1024 * 256 * 2;
    ushort* w2T  = (ushort*)p; p += (size_t)NL_ * 256 * 1024 * 2;
    float*  SCp  = (float*)p;  p += (size_t)ROWS * 4;

    wcast_kernel<<<dim3(768 / 32, 256 / 32, NL_), dim3(32, 8), 0, stream>>>(qkv_w, qkvT, 256, 768);
    wcast_kernel<<<dim3(1024 / 32, 256 / 32, NL_), dim3(32, 8), 0, stream>>>(ffn_w1, w1T, 256, 1024);
    wcast_kernel<<<dim3(256 / 32, 1024 / 32, NL_), dim3(32, 8), 0, stream>>>(ffn_w2, w2T, 1024, 256);

    sgemm_kernel<<<dim3(D_ / 64, (B_ * NT_) / 64), 256, 0, stream>>>(
        gene, w_in, b_in, X, Xb, B_ * NT_, D_, TOK_);
    cls_kernel<<<B_, 256, 0, stream>>>(coords, w_cls, b_cls, X, Xb);

    for (int l = 0; l < NL_; ++l) {
        mfma_gemm<<<dim3(768 / 128, MPAD / 128), 256, 0, stream>>>(
            Xb, qkvT + (size_t)l * 768 * 256, qkv_b + l * 768, SH, 768, 256, 0, 1);
        attn_kernel<<<dim3(H_, B_), 512, 0, stream>>>(SH, AO);
        ln_kernel<<<ROWS / 4, 256, 0, stream>>>(X, AO, ln1_g + l * D_, ln1_b + l * D_, X, Xb);
        mfma_gemm<<<dim3(1024 / 128, MPAD / 128), 256, 0, stream>>>(
            Xb, w1T + (size_t)l * 1024 * 256, ffn_b1 + l * 1024, SH, 1024, 256, 1, 1);
        mfma_gemm<<<dim3(256 / 128, MPAD / 128), 256, 0, stream>>>(
            SH, w2T + (size_t)l * 256 * 1024, ffn_b2 + l * D_, AO, 256, 1024, 0, 0);
        ln_kernel<<<ROWS / 4, 256, 0, stream>>>(X, AO, ln2_g + l * D_, ln2_b + l * D_, X, Xb);
    }

    head1_kernel<<<ROWS / 8, 256, 0, stream>>>(
        X, th1_w, th1_b, bn_g, bn_b, th2_w, th2_b, SCp);
    head2_kernel<<<dim3(4, B_), 256, 0, stream>>>(SCp, X, out);
}

// Round 7
// 1049.022 us; speedup vs baseline: 7.6619x; 1.1582x over previous
//
#include <hip/hip_runtime.h>
#include <math.h>

#define B_   64
#define TOK_ 64
#define NT_  456
#define L_   457
#define D_   256
#define H_   8
#define HD_  32
#define FF_  1024
#define NL_  4
#define PH_  32
#define MPAD 29312   // 229 * 128 (rows padded for 128-row GEMM tiles)

typedef unsigned int uint;
typedef unsigned short ushort;
typedef __bf16 v8bf __attribute__((ext_vector_type(8)));
typedef float v4f __attribute__((ext_vector_type(4)));

__device__ __forceinline__ float bu2f(ushort x) {
    return __uint_as_float(((uint)x) << 16);
}
__device__ __forceinline__ ushort f2bu(float f) {
    union { float f; uint u; } x; x.f = f;
    uint r = (x.u + 0x7fffu + ((x.u >> 16) & 1u)) >> 16;
    return (ushort)r;
}
// pack two floats to packed bf16 (RNE); hw instr if available
__device__ __forceinline__ uint pack_bf2(float a, float b) {
#if __has_builtin(__builtin_amdgcn_cvt_pk_bf16_f32)
    typedef __bf16 bf2v __attribute__((ext_vector_type(2)));
    bf2v v = __builtin_amdgcn_cvt_pk_bf16_f32(a, b);
    return *(uint*)&v;
#else
    return (uint)f2bu(a) | ((uint)f2bu(b) << 16);
#endif
}

// async global->LDS 16B copy; lds base wave-uniform, data at base + lane*16.
__device__ __forceinline__ void gload16(const void* g, void* l) {
    __builtin_amdgcn_global_load_lds(
        (const __attribute__((address_space(1))) void*)(unsigned long long)(uintptr_t)g,
        (__attribute__((address_space(3))) void*)(uint)(uintptr_t)l,
        16, 0, 0);
}

// ---------------------------------------------------------------------------
// bf16 MFMA GEMM (m97 structure): C[M,N] = A[M,K]·W^T[N,K] + bias.
// ---------------------------------------------------------------------------
__global__ __launch_bounds__(256) void mfma_gemm(
    const ushort* __restrict__ A, const ushort* __restrict__ WT,
    const float* __restrict__ bias, void* __restrict__ Cout,
    int N, int K, int relu, int obf16)
{
    __shared__ ushort As[128 * 32];
    __shared__ ushort Bs[128 * 32];
    int tid = threadIdx.x;
    int wave = tid >> 6, lane = tid & 63;
    int colblk = blockIdx.x * 128;
    int rowblk = blockIdx.y * 128;
    int wm = wave >> 1, wn = wave & 1;

    v4f acc[4][4];
#pragma unroll
    for (int i = 0; i < 4; ++i)
#pragma unroll
        for (int j = 0; j < 4; ++j) acc[i][j] = (v4f)0.0f;

    int fr = lane & 15, fq = lane >> 4;
    int scol = fq ^ (lane & 3) ^ ((lane >> 2) & 1);

    int c0 = wave * 64 + lane;
    int r0 = c0 >> 2, k0g = (c0 & 3) ^ (r0 & 3) ^ ((r0 >> 2) & 1);
    int c1 = 256 + c0;
    int r1 = c1 >> 2, k1g = (c1 & 3) ^ (r1 & 3) ^ ((r1 >> 2) & 1);

    const ushort* Ag0 = A + (size_t)(rowblk + r0) * K + k0g * 8;
    const ushort* Ag1 = A + (size_t)(rowblk + r1) * K + k1g * 8;
    const ushort* Bg0 = WT + (size_t)(colblk + r0) * K + k0g * 8;
    const ushort* Bg1 = WT + (size_t)(colblk + r1) * K + k1g * 8;
    ushort* lA0 = As + (size_t)(wave * 64) * 8;
    ushort* lA1 = As + (size_t)(256 + wave * 64) * 8;
    ushort* lB0 = Bs + (size_t)(wave * 64) * 8;
    ushort* lB1 = Bs + (size_t)(256 + wave * 64) * 8;

    for (int kt = 0; kt < K; kt += 32) {
        gload16(Ag0 + kt, lA0);
        gload16(Ag1 + kt, lA1);
        gload16(Bg0 + kt, lB0);
        gload16(Bg1 + kt, lB1);
        __syncthreads();

        v8bf a[4], b[4];
#pragma unroll
        for (int mi = 0; mi < 4; ++mi)
            a[mi] = *(const v8bf*)(As + (size_t)(wm * 64 + mi * 16 + fr) * 32 + scol * 8);
#pragma unroll
        for (int ni = 0; ni < 4; ++ni)
            b[ni] = *(const v8bf*)(Bs + (size_t)(wn * 64 + ni * 16 + fr) * 32 + scol * 8);
#pragma unroll
        for (int mi = 0; mi < 4; ++mi)
#pragma unroll
            for (int ni = 0; ni < 4; ++ni)
                acc[mi][ni] = __builtin_amdgcn_mfma_f32_16x16x32_bf16(
                    a[mi], b[ni], acc[mi][ni], 0, 0, 0);
        __syncthreads();
    }

#pragma unroll
    for (int ni = 0; ni < 4; ++ni) {
        int col = colblk + wn * 64 + ni * 16 + fr;
        float bv = bias[col];
#pragma unroll
        for (int mi = 0; mi < 4; ++mi) {
            int row = rowblk + wm * 64 + mi * 16 + fq * 4;
#pragma unroll
            for (int r = 0; r < 4; ++r) {
                float v = acc[mi][ni][r] + bv;
                if (relu) v = fmaxf(v, 0.f);
                if (obf16)
                    ((ushort*)Cout)[(size_t)(row + r) * N + col] = f2bu(v);
                else
                    ((float*)Cout)[(size_t)(row + r) * N + col] = v;
            }
        }
    }
}

// ---------------------------------------------------------------------------
__global__ __launch_bounds__(256) void wcast_kernel(
    const float* __restrict__ W, ushort* __restrict__ WT, int K, int N)
{
    __shared__ float t[32][33];
    const float* Wl = W + (size_t)blockIdx.z * K * N;
    ushort* WTl = WT + (size_t)blockIdx.z * K * N;
    int n0 = blockIdx.x * 32, k0 = blockIdx.y * 32;
    int tx = threadIdx.x, ty = threadIdx.y;
#pragma unroll
    for (int r = 0; r < 32; r += 8)
        t[ty + r][tx] = Wl[(size_t)(k0 + ty + r) * N + n0 + tx];
    __syncthreads();
#pragma unroll
    for (int r = 0; r < 32; r += 8)
        WTl[(size_t)(n0 + ty + r) * K + k0 + tx] = f2bu(t[tx][ty + r]);
}

// ---------------------------------------------------------------------------
// fp32 SGEMM for the embed GEMM only; row-remap; writes fp32 X and bf16 Xb.
// ---------------------------------------------------------------------------
__global__ __launch_bounds__(256) void sgemm_kernel(
    const float* __restrict__ A, const float* __restrict__ W,
    const float* __restrict__ bias, float* __restrict__ C,
    ushort* __restrict__ Cb, int M, int N, int K)
{
    __shared__ float As_[16][64];
    __shared__ float Bs_[16][64];
    int tid = threadIdx.x;
    int rowblk = blockIdx.y * 64;
    int colblk = blockIdx.x * 64;
    int a_row = tid & 63, a_q = tid >> 6;
    int b_kr = tid >> 4, b_cg = tid & 15;
    int rm = tid >> 4, cn = tid & 15;
    float acc[4][4] = {};
    const float* Aptr = A + (size_t)(rowblk + a_row) * K;
    for (int kt = 0; kt < K; kt += 16) {
        float4 av = *(const float4*)(Aptr + kt + a_q * 4);
        float4 bv = *(const float4*)(W + (size_t)(kt + b_kr) * N + colblk + b_cg * 4);
        As_[a_q * 4 + 0][a_row] = av.x;
        As_[a_q * 4 + 1][a_row] = av.y;
        As_[a_q * 4 + 2][a_row] = av.z;
        As_[a_q * 4 + 3][a_row] = av.w;
        *(float4*)&Bs_[b_kr][b_cg * 4] = bv;
        __syncthreads();
#pragma unroll
        for (int kk = 0; kk < 16; ++kk) {
            float4 a4 = *(const float4*)&As_[kk][rm * 4];
            float4 b4 = *(const float4*)&Bs_[kk][cn * 4];
            float ar[4] = {a4.x, a4.y, a4.z, a4.w};
            float br[4] = {b4.x, b4.y, b4.z, b4.w};
#pragma unroll
            for (int i = 0; i < 4; ++i)
#pragma unroll
                for (int j = 0; j < 4; ++j) acc[i][j] += ar[i] * br[j];
        }
        __syncthreads();
    }
    float4 bv = *(const float4*)(bias + colblk + cn * 4);
    float bb[4] = {bv.x, bv.y, bv.z, bv.w};
#pragma unroll
    for (int i = 0; i < 4; ++i) {
        int grow = rowblk + rm * 4 + i;
        size_t orow = (size_t)(grow + grow / NT_ + 1);
        float4 r;
        r.x = acc[i][0] + bb[0]; r.y = acc[i][1] + bb[1];
        r.z = acc[i][2] + bb[2]; r.w = acc[i][3] + bb[3];
        *(float4*)(C + orow * N + colblk + cn * 4) = r;
        ushort4 h;
        h.x = f2bu(r.x); h.y = f2bu(r.y); h.z = f2bu(r.z); h.w = f2bu(r.w);
        *(ushort4*)(Cb + orow * N + colblk + cn * 4) = h;
    }
}

__global__ __launch_bounds__(256) void cls_kernel(
    const float* __restrict__ coords, const float* __restrict__ w_cls,
    const float* __restrict__ b_cls, float* __restrict__ X,
    ushort* __restrict__ Xb)
{
    int b = blockIdx.x;
    int t = threadIdx.x;
    float c0 = coords[b * 3 + 0], c1 = coords[b * 3 + 1], c2 = coords[b * 3 + 2];
    float v = c0 * w_cls[t] + c1 * w_cls[D_ + t] + c2 * w_cls[2 * D_ + t] + b_cls[t];
    X[(size_t)b * L_ * D_ + t] = v;
    Xb[(size_t)b * L_ * D_ + t] = f2bu(v);
}

// ---------------------------------------------------------------------------
// MFMA attention v4 (flash-style): one block per (b,h), 512 threads (8 waves).
// K and V^T staged once into LDS (67 KB); each wave owns 16-row q-tiles
// end-to-end with NO barriers after staging. Per 32-k chunk: 2 QK MFMAs
// (swapped operands -> lane holds 4 consecutive k for q=fr), exp, packed
// b64 stores into per-wave P-scratch, one b128 read back as PV A-frag,
// 2 PV MFMAs. 76.8 KB LDS -> 2 blocks/CU (16 waves). Row sums in registers.
// Bank balance (quads): P-read quad=(5fr+fq)%8 uniform; K/Vt reads same.
// ---------------------------------------------------------------------------
__global__ __launch_bounds__(512) void attn_kernel(
    const ushort* __restrict__ qkv, float* __restrict__ out)
{
    __shared__ __align__(16) ushort Ks[464][40];    // 36.3 KB
    __shared__ __align__(16) ushort Vt[32][488];    // 30.5 KB
    __shared__ __align__(16) ushort Ps[8][16][40];  // 10.0 KB per-wave P scratch

    int h = blockIdx.x, b = blockIdx.y;
    int tid = threadIdx.x;
    int wave = tid >> 6, lane = tid & 63;
    int fr = lane & 15, fq = lane >> 4;
    const float scale = 0.17677669529663687f;
    float slope = (h < 4) ? 1.0f : 0.5f;
    const ushort* base = qkv + (size_t)b * L_ * 768;

    // stage K rows 0..463 (zero-fill >= 457), pitch 40 ushorts
    for (int j = tid >> 2; j < 464; j += 128) {
        int c8 = (tid & 3) * 8;
        uint4 u = make_uint4(0u, 0u, 0u, 0u);
        if (j < L_) u = *(const uint4*)(base + (size_t)j * 768 + 256 + h * 32 + c8);
        *(uint4*)&Ks[j][c8] = u;
    }
    // stage V transposed; per-wave 64 consecutive j -> balanced banks
    for (int m = wave; m < 32; m += 8) {
        int dg = (m >> 3) * 8, jb = m & 7;
        int j = jb * 64 + lane;
        uint4 u = make_uint4(0u, 0u, 0u, 0u);
        if (j < L_) u = *(const uint4*)(base + (size_t)j * 768 + 512 + h * 32 + dg);
        if (j < 488) {
            const ushort* pu = (const ushort*)&u;
#pragma unroll
            for (int e = 0; e < 8; ++e) Vt[dg + e][j] = pu[e];
        }
    }
    __syncthreads();

    // each wave handles q-tiles t = wave, wave+8, ... (29 tiles of 16 rows)
    for (int t = wave; t < 29; t += 8) {
        int q0 = t * 16;
        // Q fragment straight from global: 16B per lane
        uint4 qu = *(const uint4*)(base + (size_t)(q0 + fr) * 768 + h * 32 + fq * 8);
        v8bf qfrag = *(v8bf*)&qu;
        float fmyq = (float)(q0 + fr);
        float psum = 0.f;
        v4f o0 = (v4f)0.0f, o1 = (v4f)0.0f;

        // full 32-k chunks (k < 448)
        for (int kc = 0; kc < 14; ++kc) {
            v8bf kf0 = *(const v8bf*)&Ks[kc * 32 + fr][fq * 8];
            v8bf kf1 = *(const v8bf*)&Ks[kc * 32 + 16 + fr][fq * 8];
            v4f d0 = (v4f)0.0f, d1 = (v4f)0.0f;
            d0 = __builtin_amdgcn_mfma_f32_16x16x32_bf16(kf0, qfrag, d0, 0, 0, 0);
            d1 = __builtin_amdgcn_mfma_f32_16x16x32_bf16(kf1, qfrag, d1, 0, 0, 0);
            float ke = (float)(kc * 32 + 4 * fq);
            float pe[4], po[4];
#pragma unroll
            for (int r = 0; r < 4; ++r) {
                pe[r] = __expf(d0[r] * scale - slope * fabsf(fmyq - (ke + (float)r)));
                po[r] = __expf(d1[r] * scale - slope * fabsf(fmyq - (ke + 16.0f + (float)r)));
                psum += pe[r] + po[r];
            }
            uint2 ue, uo;
            ue.x = pack_bf2(pe[0], pe[1]); ue.y = pack_bf2(pe[2], pe[3]);
            uo.x = pack_bf2(po[0], po[1]); uo.y = pack_bf2(po[2], po[3]);
            *(uint2*)&Ps[wave][fr][4 * fq] = ue;
            *(uint2*)&Ps[wave][fr][16 + 4 * fq] = uo;
            v8bf pfrag = *(const v8bf*)&Ps[wave][fr][8 * fq];
            v8bf vf0 = *(const v8bf*)&Vt[fr][kc * 32 + fq * 8];
            v8bf vf1 = *(const v8bf*)&Vt[16 + fr][kc * 32 + fq * 8];
            o0 = __builtin_amdgcn_mfma_f32_16x16x32_bf16(pfrag, vf0, o0, 0, 0, 0);
            o1 = __builtin_amdgcn_mfma_f32_16x16x32_bf16(pfrag, vf1, o1, 0, 0, 0);
        }
        // tail chunk: k 448..463 (tile 28), upper half zero
        {
            v8bf kf0 = *(const v8bf*)&Ks[448 + fr][fq * 8];
            v4f d0 = (v4f)0.0f;
            d0 = __builtin_amdgcn_mfma_f32_16x16x32_bf16(kf0, qfrag, d0, 0, 0, 0);
            float pe[4];
#pragma unroll
            for (int r = 0; r < 4; ++r) {
                int k = 448 + 4 * fq + r;
                pe[r] = (k < L_)
                    ? __expf(d0[r] * scale - slope * fabsf(fmyq - (float)k)) : 0.f;
                psum += pe[r];
            }
            uint2 ue;
            ue.x = pack_bf2(pe[0], pe[1]); ue.y = pack_bf2(pe[2], pe[3]);
            *(uint2*)&Ps[wave][fr][4 * fq] = ue;
            *(uint2*)&Ps[wave][fr][16 + 4 * fq] = make_uint2(0u, 0u);
            v8bf pfrag = *(const v8bf*)&Ps[wave][fr][8 * fq];
            v8bf vf0 = *(const v8bf*)&Vt[fr][448 + fq * 8];
            v8bf vf1 = *(const v8bf*)&Vt[16 + fr][448 + fq * 8];
            o0 = __builtin_amdgcn_mfma_f32_16x16x32_bf16(pfrag, vf0, o0, 0, 0, 0);
            o1 = __builtin_amdgcn_mfma_f32_16x16x32_bf16(pfrag, vf1, o1, 0, 0, 0);
        }

        // row sums: reduce across fq, then redistribute to C-layout rows
        psum += __shfl_xor(psum, 16);
        psum += __shfl_xor(psum, 32);
#pragma unroll
        for (int r = 0; r < 4; ++r) {
            int q = q0 + 4 * fq + r;
            float rsum = __shfl(psum, 4 * fq + r);
            if (q < L_) {
                float inv = 1.0f / rsum;
                out[(size_t)(b * L_ + q) * D_ + h * 32 + fr] = o0[r] * inv;
                out[(size_t)(b * L_ + q) * D_ + h * 32 + 16 + fr] = o1[r] * inv;
            }
        }
    }
}

// ---------------------------------------------------------------------------
// Fused residual+LN: wave per row, shuffle-only, 4 rows/block.
// ---------------------------------------------------------------------------
__global__ __launch_bounds__(256) void ln_kernel(
    const float* __restrict__ res, const float* __restrict__ y,
    const float* __restrict__ g, const float* __restrict__ bb,
    float* __restrict__ xout, ushort* __restrict__ xbout)
{
    int row = blockIdx.x * 4 + (threadIdx.x >> 6);
    int lane = threadIdx.x & 63;
    size_t off = (size_t)row * D_ + lane * 4;
    float4 rv = *(const float4*)(res + off);
    float4 yv = *(const float4*)(y + off);
    float4 v;
    v.x = rv.x + yv.x; v.y = rv.y + yv.y; v.z = rv.z + yv.z; v.w = rv.w + yv.w;

    float s = v.x + v.y + v.z + v.w;
#pragma unroll
    for (int o = 1; o < 64; o <<= 1) s += __shfl_xor(s, o);
    float mean = s * (1.0f / 256.0f);

    float4 d;
    d.x = v.x - mean; d.y = v.y - mean; d.z = v.z - mean; d.w = v.w - mean;
    float sq = d.x * d.x + d.y * d.y + d.z * d.z + d.w * d.w;
#pragma unroll
    for (int o = 1; o < 64; o <<= 1) sq += __shfl_xor(sq, o);
    float rstd = rsqrtf(sq * (1.0f / 256.0f) + 1e-5f);

    float4 gv = *(const float4*)(g + lane * 4);
    float4 bv = *(const float4*)(bb + lane * 4);
    float4 o;
    o.x = d.x * rstd * gv.x + bv.x;
    o.y = d.y * rstd * gv.y + bv.y;
    o.z = d.z * rstd * gv.z + bv.z;
    o.w = d.w * rstd * gv.w + bv.w;
    *(float4*)(xout + off) = o;
    ushort4 hb;
    hb.x = f2bu(o.x); hb.y = f2bu(o.y); hb.z = f2bu(o.z); hb.w = f2bu(o.w);
    *(ushort4*)(xbout + off) = hb;
}

__global__ __launch_bounds__(256) void head1_kernel(
    const float* __restrict__ X, const float* __restrict__ w1,
    const float* __restrict__ b1, const float* __restrict__ bng,
    const float* __restrict__ bnb, const float* __restrict__ w2,
    const float* __restrict__ b2, float* __restrict__ SCp)
{
    int row = blockIdx.x * 8 + (threadIdx.x >> 5);
    int j = threadIdx.x & 31;
    const float* x = X + (size_t)row * D_;
    float acc = 0.f;
    for (int d = 0; d < D_; ++d) acc += x[d] * w1[d * PH_ + j];
    acc += b1[j];
    float hb = acc * (bng[j] * rsqrtf(1.0f + 1e-5f)) + bnb[j];
    const float c = 0.7978845608028654f;
    float t = tanhf(c * (hb + 0.044715f * hb * hb * hb));
    float gl = 0.5f * hb * (1.0f + t);
    float sp = gl * w2[j];
#pragma unroll
    for (int o = 16; o > 0; o >>= 1) sp += __shfl_xor(sp, o);
    if (j == 0) SCp[row] = sp + b2[0];
}

// ---------------------------------------------------------------------------
// head2: block (colgroup, b); 64 cols x 4 L-partitions per block.
// ---------------------------------------------------------------------------
__global__ __launch_bounds__(256) void head2_kernel(
    const float* __restrict__ SCp, const float* __restrict__ X,
    float* __restrict__ outp)
{
    int cg = blockIdx.x, b = blockIdx.y;
    int tid = threadIdx.x;
    __shared__ float wbuf[L_];
    __shared__ float r1[4], r2[4];
    __shared__ float part[4][64];
    const float* s = SCp + (size_t)b * L_;

    float m = -1e30f;
    for (int j = tid; j < L_; j += 256) m = fmaxf(m, s[j]);
#pragma unroll
    for (int o = 1; o < 64; o <<= 1) m = fmaxf(m, __shfl_xor(m, o));
    if ((tid & 63) == 0) r1[tid >> 6] = m;
    __syncthreads();
    m = fmaxf(fmaxf(r1[0], r1[1]), fmaxf(r1[2], r1[3]));

    float sum = 0.f;
    for (int j = tid; j < L_; j += 256) {
        float e = __expf(s[j] - m);
        wbuf[j] = e;
        sum += e;
    }
#pragma unroll
    for (int o = 1; o < 64; o <<= 1) sum += __shfl_xor(sum, o);
    if ((tid & 63) == 0) r2[tid >> 6] = sum;
    __syncthreads();
    float inv = 1.0f / (r2[0] + r2[1] + r2[2] + r2[3]);

    int c = tid & 63, pt = tid >> 6;
    int col = cg * 64 + c;
    float acc = 0.f;
    const float* xb = X + (size_t)b * L_ * D_ + col;
    for (int l = pt; l < L_; l += 4) acc += wbuf[l] * xb[(size_t)l * D_];
    part[pt][c] = acc;
    __syncthreads();
    if (pt == 0)
        outp[b * D_ + col] = (part[0][c] + part[1][c] + part[2][c] + part[3][c]) * inv;
}

// ---------------------------------------------------------------------------
extern "C" void kernel_launch(void* const* d_in, const int* in_sizes, int n_in,
                              void* d_out, int out_size, void* d_ws, size_t ws_size,
                              hipStream_t stream)
{
    const float* gene   = (const float*)d_in[0];
    const float* coords = (const float*)d_in[1];
    const float* w_in   = (const float*)d_in[2];
    const float* b_in   = (const float*)d_in[3];
    const float* w_cls  = (const float*)d_in[4];
    const float* b_cls  = (const float*)d_in[5];
    const float* qkv_w  = (const float*)d_in[6];
    const float* qkv_b  = (const float*)d_in[7];
    const float* ln1_g  = (const float*)d_in[8];
    const float* ln1_b  = (const float*)d_in[9];
    const float* ffn_w1 = (const float*)d_in[10];
    const float* ffn_b1 = (const float*)d_in[11];
    const float* ffn_w2 = (const float*)d_in[12];
    const float* ffn_b2 = (const float*)d_in[13];
    const float* ln2_g  = (const float*)d_in[14];
    const float* ln2_b  = (const float*)d_in[15];
    const float* th1_w  = (const float*)d_in[16];
    const float* th1_b  = (const float*)d_in[17];
    const float* bn_g   = (const float*)d_in[18];
    const float* bn_b   = (const float*)d_in[19];
    const float* th2_w  = (const float*)d_in[20];
    const float* th2_b  = (const float*)d_in[21];
    float* out = (float*)d_out;

    const int ROWS = B_ * L_;   // 29248
    char* p = (char*)d_ws;
    float*  X    = (float*)p;  p += (size_t)MPAD * 256 * 4;
    float*  AO   = (float*)p;  p += (size_t)MPAD * 256 * 4;
    ushort* Xb   = (ushort*)p; p += (size_t)MPAD * 256 * 2;
    ushort* SH   = (ushort*)p; p += (size_t)MPAD * 1024 * 2;
    ushort* qkvT = (ushort*)p; p += (size_t)NL_ * 768 * 256 * 2;
    ushort* w1T  = (ushort*)p; p += (size_t)NL_ * 1024 * 256 * 2;
    ushort* w2T  = (ushort*)p; p += (size_t)NL_ * 256 * 1024 * 2;
    float*  SCp  = (float*)p;  p += (size_t)ROWS * 4;

    wcast_kernel<<<dim3(768 / 32, 256 / 32, NL_), dim3(32, 8), 0, stream>>>(qkv_w, qkvT, 256, 768);
    wcast_kernel<<<dim3(1024 / 32, 256 / 32, NL_), dim3(32, 8), 0, stream>>>(ffn_w1, w1T, 256, 1024);
    wcast_kernel<<<dim3(256 / 32, 1024 / 32, NL_), dim3(32, 8), 0, stream>>>(ffn_w2, w2T, 1024, 256);

    sgemm_kernel<<<dim3(D_ / 64, (B_ * NT_) / 64), 256, 0, stream>>>(
        gene, w_in, b_in, X, Xb, B_ * NT_, D_, TOK_);
    cls_kernel<<<B_, 256, 0, stream>>>(coords, w_cls, b_cls, X, Xb);

    for (int l = 0; l < NL_; ++l) {
        mfma_gemm<<<dim3(768 / 128, MPAD / 128), 256, 0, stream>>>(
            Xb, qkvT + (size_t)l * 768 * 256, qkv_b + l * 768, SH, 768, 256, 0, 1);
        attn_kernel<<<dim3(H_, B_), 512, 0, stream>>>(SH, AO);
        ln_kernel<<<ROWS / 4, 256, 0, stream>>>(X, AO, ln1_g + l * D_, ln1_b + l * D_, X, Xb);
        mfma_gemm<<<dim3(1024 / 128, MPAD / 128), 256, 0, stream>>>(
            Xb, w1T + (size_t)l * 1024 * 256, ffn_b1 + l * 1024, SH, 1024, 256, 1, 1);
        mfma_gemm<<<dim3(256 / 128, MPAD / 128), 256, 0, stream>>>(
            SH, w2T + (size_t)l * 256 * 1024, ffn_b2 + l * D_, AO, 256, 1024, 0, 0);
        ln_kernel<<<ROWS / 4, 256, 0, stream>>>(X, AO, ln2_g + l * D_, ln2_b + l * D_, X, Xb);
    }

    head1_kernel<<<ROWS / 8, 256, 0, stream>>>(
        X, th1_w, th1_b, bn_g, bn_b, th2_w, th2_b, SCp);
    head2_kernel<<<dim3(4, B_), 256, 0, stream>>>(SCp, X, out);
}